// Round 12
// baseline (474.593 us; speedup 1.0000x reference)
//
#include <hip/hip_runtime.h>
#include <hip/hip_bf16.h>

typedef __hip_bfloat16 bf16;
typedef __attribute__((ext_vector_type(8))) __bf16 bf16x8;
typedef __attribute__((ext_vector_type(4))) float f32x4;

#define MFMA16(a, b, c) __builtin_amdgcn_mfma_f32_16x16x32_bf16((a), (b), (c), 0, 0, 0)

static __device__ __forceinline__ void gload_lds16(const void* g, void* l) {
    typedef const __attribute__((address_space(1))) unsigned gq_t;
    typedef __attribute__((address_space(3))) unsigned ls_t;
    __builtin_amdgcn_global_load_lds((gq_t*)g, (ls_t*)l, 16, 0, 0);
}

static __device__ __forceinline__ unsigned short f2bfbits(float f) {
    bf16 h = __float2bfloat16(f);
    return *reinterpret_cast<unsigned short*>(&h);
}

// ---------------- prepass: f32 -> bf16 cast of x ----------------
__global__ __launch_bounds__(256) void cvt_bf16_kernel(const float* __restrict__ in,
                                                       bf16* __restrict__ out, int n) {
    int i = (blockIdx.x * 256 + threadIdx.x) * 8;
    if (i < n) {
        float4 a = *reinterpret_cast<const float4*>(in + i);
        float4 b = *reinterpret_cast<const float4*>(in + i + 4);
        bf16 tmp[8];
        tmp[0] = __float2bfloat16(a.x); tmp[1] = __float2bfloat16(a.y);
        tmp[2] = __float2bfloat16(a.z); tmp[3] = __float2bfloat16(a.w);
        tmp[4] = __float2bfloat16(b.x); tmp[5] = __float2bfloat16(b.y);
        tmp[6] = __float2bfloat16(b.z); tmp[7] = __float2bfloat16(b.w);
        *reinterpret_cast<uint4*>(out + i) = *reinterpret_cast<const uint4*>(tmp);
    }
}

// ---------------- prepass: transpose Wq|Wk|Wv -> [3072][2048] bf16 ----------------
__global__ __launch_bounds__(256) void transpose_wqkv_kernel(const float* __restrict__ Wq,
                                                             const float* __restrict__ Wk,
                                                             const float* __restrict__ Wv,
                                                             bf16* __restrict__ out) {
    __shared__ float tile[32][33];
    int k0 = blockIdx.x * 32;   // along K (2048)
    int n0 = blockIdx.y * 32;   // along N (3072)
    int tx = threadIdx.x & 31, ty = threadIdx.x >> 5;  // 32 x 8
#pragma unroll
    for (int i = 0; i < 4; ++i) {
        int k = k0 + ty + i * 8, n = n0 + tx;
        float v;
        if (n < 2048)      v = Wq[(size_t)k * 2048 + n];
        else if (n < 2560) v = Wk[(size_t)k * 512 + (n - 2048)];
        else               v = Wv[(size_t)k * 512 + (n - 2560)];
        tile[ty + i * 8][tx] = v;
    }
    __syncthreads();
#pragma unroll
    for (int i = 0; i < 4; ++i)
        out[(size_t)(n0 + ty + i * 8) * 2048 + k0 + tx] = __float2bfloat16(tile[tx][ty + i * 8]);
}

// ---------------- prepass: transpose square W (2048x2048) -> bf16 ----------------
__global__ __launch_bounds__(256) void transpose_w_kernel(const float* __restrict__ in,
                                                          bf16* __restrict__ out) {
    __shared__ float tile[32][33];
    int k0 = blockIdx.x * 32, n0 = blockIdx.y * 32;
    int tx = threadIdx.x & 31, ty = threadIdx.x >> 5;
#pragma unroll
    for (int i = 0; i < 4; ++i)
        tile[ty + i * 8][tx] = in[(size_t)(k0 + ty + i * 8) * 2048 + n0 + tx];
    __syncthreads();
#pragma unroll
    for (int i = 0; i < 4; ++i)
        out[(size_t)(n0 + ty + i * 8) * 2048 + k0 + tx] = __float2bfloat16(tile[tx][ty + i * 8]);
}

// ---------------- 8-phase GEMM template (R6-verified best): C = A[M,K] @ BT[N,K]^T ----
template <int NFRAG, bool OUT_F32>
__global__ __launch_bounds__(512, 2) void gemm8p_kernel(const bf16* __restrict__ A,
                                                        const bf16* __restrict__ BT,
                                                        void* __restrict__ Cv,
                                                        int M, int N, int K, int nbn) {
    constexpr int BN = NFRAG * 64;
    constexpr int PB = NFRAG;          // B pieces per K-tile (1 gload/thread each)
    __shared__ bf16 As[2][256 * 64];
    __shared__ bf16 Bs[2][BN * 64];
    int t = threadIdx.x;
    int lane = t & 63, w = t >> 6;
    int wm = w >> 2, wn = w & 3;
    int lr = lane & 15, lq = lane >> 4;
    int lin = blockIdx.x;
    int cpx = gridDim.x >> 3;          // bijective XCD-chunked swizzle (grid % 8 == 0)
    int wg = (lin & 7) * cpx + (lin >> 3);
    int bm = wg / nbn, bn = wg % nbn;
    const bf16* Ab = A + (size_t)bm * 256 * K;
    const bf16* Bb = BT + (size_t)bn * BN * K;

    auto stA = [&](int slot, int kt, int piece) {
        int idx = piece * 512 + t;
        int r = idx >> 3, c8 = idx & 7;
        gload_lds16(Ab + (size_t)r * K + kt * 64 + ((c8 ^ (r & 7)) * 8), &As[slot][idx * 8]);
    };
    auto stB = [&](int slot, int kt, int piece) {
        int idx = piece * 512 + t;
        int r = idx >> 3, c8 = idx & 7;
        gload_lds16(Bb + (size_t)r * K + kt * 64 + ((c8 ^ (r & 7)) * 8), &Bs[slot][idx * 8]);
    };

    f32x4 acc[8][NFRAG] = {};
    bf16x8 bq[NFRAG][2], af[2][2];

    auto readB = [&](int slot) {
#pragma unroll
        for (int n = 0; n < NFRAG; ++n)
#pragma unroll
            for (int ks = 0; ks < 2; ++ks) {
                int ro = wn * (NFRAG * 16) + n * 16 + lr;
                int ch = (ks * 4 + lq) ^ (ro & 7);
                bq[n][ks] = *reinterpret_cast<const bf16x8*>(&Bs[slot][ro * 64 + ch * 8]);
            }
    };
    auto readA = [&](int mbase, int slot) {
#pragma unroll
        for (int mi = 0; mi < 2; ++mi)
#pragma unroll
            for (int ks = 0; ks < 2; ++ks) {
                int ro = wm * 128 + (mbase + mi) * 16 + lr;
                int ch = (ks * 4 + lq) ^ (ro & 7);
                af[mi][ks] = *reinterpret_cast<const bf16x8*>(&As[slot][ro * 64 + ch * 8]);
            }
    };
    auto mf = [&](int mbase) {
#pragma unroll
        for (int mi = 0; mi < 2; ++mi)
#pragma unroll
            for (int n = 0; n < NFRAG; ++n)
#pragma unroll
                for (int ks = 0; ks < 2; ++ks)
                    acc[mbase + mi][n] = MFMA16(af[mi][ks], bq[n][ks], acc[mbase + mi][n]);
    };

#define GATE_PB()                                                          \
    do {                                                                   \
        if constexpr (NFRAG == 4) asm volatile("s_waitcnt vmcnt(4)" ::: "memory"); \
        else                      asm volatile("s_waitcnt vmcnt(3)" ::: "memory"); \
    } while (0)
#define PHASE_TAIL()                                                       \
    do {                                                                   \
        __builtin_amdgcn_s_barrier();                                      \
        asm volatile("s_waitcnt lgkmcnt(0)" ::: "memory");                 \
    } while (0)
#define MFMA_CLUSTER(mb)                                                   \
    do {                                                                   \
        __builtin_amdgcn_s_setprio(1);                                     \
        mf(mb);                                                            \
        __builtin_amdgcn_s_setprio(0);                                     \
        __builtin_amdgcn_s_barrier();                                      \
    } while (0)

    int nkt = K >> 6;
#pragma unroll
    for (int p = 0; p < 4; ++p) stA(0, 0, p);
#pragma unroll
    for (int p = 0; p < PB; ++p) stB(0, 0, p);
#pragma unroll
    for (int p = 0; p < PB; ++p) stB(1, 1, p);
    GATE_PB();
    __builtin_amdgcn_s_barrier();

    int nI = nkt >> 1;
    for (int I = 0; I < nI; ++I) {
        int T = I << 1;
        bool s2 = (T + 2) < nkt, s3 = (T + 3) < nkt;
        readB(0); readA(0, 0);
#pragma unroll
        for (int p = 0; p < 4; ++p) stA(1, T + 1, p);
        PHASE_TAIL();
        MFMA_CLUSTER(0);
        readA(2, 0);
        if (s2) { stB(0, T + 2, 0); stB(0, T + 2, 1); }
        PHASE_TAIL();
        MFMA_CLUSTER(2);
        readA(4, 0);
        if (s2) {
#pragma unroll
            for (int p = 2; p < PB; ++p) stB(0, T + 2, p);
        }
        PHASE_TAIL();
        MFMA_CLUSTER(4);
        readA(6, 0);
        if (s2) GATE_PB();
        else    asm volatile("s_waitcnt vmcnt(0)" ::: "memory");
        PHASE_TAIL();
        MFMA_CLUSTER(6);
        readB(1); readA(0, 1);
        if (s2) {
#pragma unroll
            for (int p = 0; p < 4; ++p) stA(0, T + 2, p);
        }
        PHASE_TAIL();
        MFMA_CLUSTER(0);
        readA(2, 1);
        if (s3) { stB(1, T + 3, 0); stB(1, T + 3, 1); }
        PHASE_TAIL();
        MFMA_CLUSTER(2);
        readA(4, 1);
        if (s3) {
#pragma unroll
            for (int p = 2; p < PB; ++p) stB(1, T + 3, p);
        }
        PHASE_TAIL();
        MFMA_CLUSTER(4);
        readA(6, 1);
        if (s3) GATE_PB();
        else    asm volatile("s_waitcnt vmcnt(0)" ::: "memory");
        PHASE_TAIL();
        MFMA_CLUSTER(6);
    }
#undef GATE_PB
#undef PHASE_TAIL
#undef MFMA_CLUSTER

#pragma unroll
    for (int m = 0; m < 8; ++m)
#pragma unroll
        for (int n = 0; n < NFRAG; ++n) {
            int row = bm * 256 + wm * 128 + m * 16 + lq * 4;
            int col = bn * BN + wn * (NFRAG * 16) + n * 16 + lr;
#pragma unroll
            for (int j = 0; j < 4; ++j) {
                if (OUT_F32)
                    ((float*)Cv)[(size_t)(row + j) * N + col] = acc[m][n][j];
                else
                    ((bf16*)Cv)[(size_t)(row + j) * N + col] = __float2bfloat16(acc[m][n][j]);
            }
        }
}

// ---------------- RMSNorm + RoPE for Q and K only (V handled by vtrans) ----------------
__global__ __launch_bounds__(256) void normrope_kernel(const bf16* __restrict__ qkv,
                                                       const float* __restrict__ cosT,
                                                       const float* __restrict__ sinT,
                                                       const float* __restrict__ qnw,
                                                       const float* __restrict__ knw,
                                                       bf16* __restrict__ qh,
                                                       bf16* __restrict__ kh) {
    int t = threadIdx.x;
    int lane = t & 63, wv = t >> 6;
    int blk = blockIdx.x;
    int r = blk / 5;
    int s = (blk % 5) * 4 + wv;     // slot 0..19: 0-15 Q heads, 16-19 K groups
    int b = r >> 12, l = r & 4095;
    int e0 = lane * 2;
    const bf16* src = qkv + (size_t)r * 3072 + s * 128;
    ushort2 xu = *reinterpret_cast<const ushort2*>(src + e0);
    float v0 = __uint_as_float((unsigned)xu.x << 16);
    float v1 = __uint_as_float((unsigned)xu.y << 16);
    float ss = v0 * v0 + v1 * v1;
#pragma unroll
    for (int d = 1; d < 64; d <<= 1) ss += __shfl_xor(ss, d, 64);
    float rn = rsqrtf(ss * (1.0f / 128.0f) + 1e-6f);
    const float* wn = (s < 16) ? qnw : knw;
    float2 wv2 = *reinterpret_cast<const float2*>(wn + e0);
    float xn0 = v0 * rn * wv2.x;
    float xn1 = v1 * rn * wv2.y;
    float xp0 = __shfl_xor(xn0, 32, 64);
    float xp1 = __shfl_xor(xn1, 32, 64);
    float r0 = (lane < 32) ? -xp0 : xp0;
    float r1 = (lane < 32) ? -xp1 : xp1;
    float2 c2 = *reinterpret_cast<const float2*>(cosT + (size_t)l * 128 + e0);
    float2 s2 = *reinterpret_cast<const float2*>(sinT + (size_t)l * 128 + e0);
    float o0 = xn0 * c2.x + r0 * s2.x;
    float o1 = xn1 * c2.y + r1 * s2.y;
    ushort2 ou;
    if (s < 16) {
        const float scl = 0.0625f * 1.44269504088896f;  // SCALE * log2(e) folded into q
        ou.x = f2bfbits(o0 * scl);
        ou.y = f2bfbits(o1 * scl);
        bf16* dst = qh + ((size_t)(b * 16 + s) * 4096 + l) * 128;
        *reinterpret_cast<ushort2*>(dst + e0) = ou;
    } else {
        int g = s - 16;
        ou.x = f2bfbits(o0);
        ou.y = f2bfbits(o1);
        int sw = (l & 7) << 3;   // bits >=3: pair adjacency + 4B alignment preserved
        bf16* dst = kh + ((size_t)(b * 4 + g) * 4096 + l) * 128;
        *reinterpret_cast<ushort2*>(dst + (e0 ^ sw)) = ou;
    }
}

// ---------------- V transpose via LDS (coalesced both sides) ----------------
__global__ __launch_bounds__(256) void vtrans_kernel(const bf16* __restrict__ qkv,
                                                     bf16* __restrict__ vt) {
    __shared__ bf16 tile[64][132];   // pad 4 elems: row stride 264 B
    int t = threadIdx.x;
    int l0 = blockIdx.x * 64;
    int bg = blockIdx.y;             // b*4+g
    int b = bg >> 2, g = bg & 3;
    const bf16* src = qkv + ((size_t)(b * 4096 + l0)) * 3072 + 2560 + g * 128;
#pragma unroll
    for (int i = 0; i < 4; ++i) {
        int c = i * 256 + t;
        int r = c >> 4, c16 = c & 15;
        uint4 v = *reinterpret_cast<const uint4*>(src + (size_t)r * 3072 + c16 * 8);
        *reinterpret_cast<uint2*>(&tile[r][c16 * 8]) = make_uint2(v.x, v.y);
        *reinterpret_cast<uint2*>(&tile[r][c16 * 8 + 4]) = make_uint2(v.z, v.w);
    }
    __syncthreads();
    bf16* dst = vt + (size_t)bg * 128 * 4096 + l0;
    int cj = t & 63;
    int pos = (cj & 0x23) | ((cj & 16) >> 2) | ((cj & 12) << 1);  // sigma(cj)
#pragma unroll
    for (int dd = 0; dd < 32; ++dd) {
        int d = (t >> 6) * 32 + dd;
        dst[(size_t)d * 4096 + (pos ^ ((d & 7) << 3))] = tile[cj][d];
    }
}

// ---------------- sliding-window flash attention: 4 q-groups per wave ----------------
// QBLK=256 (4 waves x 64 q-rows), KVBLK=64, dbuf LDS staging, counted vmcnt(8) gate.
// Swapped QK^T processed in two group-PAIRS (S-live = 32 VGPRs/pair); Q fragments
// re-loaded from L2 per tile (no resident aq -> VGPR budget); V fragments shared by
// all 4 groups in PV. LDS bytes/MFMA: 48 reads / 128 MFMA vs prior 32/64.
__global__ __launch_bounds__(256, 2) void attn_kernel(const bf16* __restrict__ qh,
                                                      const bf16* __restrict__ kh,
                                                      const bf16* __restrict__ vt,
                                                      bf16* __restrict__ ao) {
    __shared__ bf16 Ks[2][64 * 128];    // 32 KiB
    __shared__ bf16 Vs[2][128 * 64];    // 32 KiB -> 64 KiB total
    int t = threadIdx.x;
    int lane = t & 63, w = t >> 6;      // 4 waves
    int lr = lane & 15, lq = lane >> 4;
    int bid = blockIdx.x;
    int bh = (bid & 7) * 4 + (bid >> 7);     // XCD-resident K/V mapping (bijective, 512 blocks)
    int qs = ((bid >> 3) & 15) * 256;
    int b = bh >> 4, h = bh & 15, g = h >> 2;
    int row0 = qs + w * 64;                  // wave owns 64 q-rows (4 groups of 16)
    const bf16* qp = qh + ((size_t)(b * 16 + h) * 4096 + row0) * 128;
    const bf16* kp = kh + (size_t)(b * 4 + g) * 4096 * 128;
    const bf16* vp = vt + (size_t)(b * 4 + g) * 128 * 4096;

    f32x4 o[4][8] = {};                      // [group][dt]
    float lsum[4] = {0.f, 0.f, 0.f, 0.f};
    unsigned pk[4][4][2];                    // [group][jt][half]
    int t0w = max(0, row0 - 1023) >> 6;      // same for all 4 groups (span 48 < 64)
    int t1w = row0 >> 6;                     // diagonal tile (all groups)
    int t0 = max(0, qs - 1023) >> 6;         // block-level range
    int t1 = (qs + 255) >> 6;

    auto stage = [&](int buf, int kt) {
        int j0 = kt * 64;
        const bf16* kg = kp + (size_t)j0 * 128;  // contiguous 16 KB (pre-swizzled)
#pragma unroll
        for (int i = 0; i < 4; ++i) {
            int c = i * 256 + t;                 // 0..1023 chunks of 16B
            gload_lds16(kg + c * 8, &Ks[buf][c * 8]);
        }
#pragma unroll
        for (int i = 0; i < 4; ++i) {
            int c = i * 256 + t;
            int d = c >> 3, co = (c & 7) * 8;
            gload_lds16(vp + (size_t)d * 4096 + j0 + co, &Vs[buf][c * 8]);
        }
    };

    stage(0, t0);
    int cur = 0;

    for (int kt = t0; kt <= t1; ++kt) {
        if (kt < t1) {
            stage(cur ^ 1, kt + 1);              // prefetch next tile (8 loads in flight)
            asm volatile("s_waitcnt vmcnt(8)" ::: "memory");   // certify cur only
        } else {
            asm volatile("s_waitcnt vmcnt(0)" ::: "memory");
        }
        __builtin_amdgcn_s_barrier();            // all waves certified -> cur resident
        if (kt >= t0w && kt <= t1w) {            // wave-uniform activity window
            int j0 = kt * 64;
            bool mwin = (kt <= t0w + 1);         // window-start boundary tiles
            bool mdia = (kt == t1w);             // diagonal tile
            // ---- two group-pairs: S^T = K Q^T, softmax, pack ----
#pragma unroll
            for (int pp = 0; pp < 2; ++pp) {
                f32x4 s0[4] = {}, s1[4] = {};
                __builtin_amdgcn_s_setprio(1);
#pragma unroll
                for (int kk = 0; kk < 4; ++kk) {
                    // Q fragments for the two groups of this pair (L2-hot re-load)
                    bf16x8 qf0 = *reinterpret_cast<const bf16x8*>(
                        qp + (size_t)((2 * pp) * 16 + lr) * 128 + kk * 32 + lq * 8);
                    bf16x8 qf1 = *reinterpret_cast<const bf16x8*>(
                        qp + (size_t)((2 * pp + 1) * 16 + lr) * 128 + kk * 32 + lq * 8);
#pragma unroll
                    for (int jt = 0; jt < 4; ++jt) {
                        int r = jt * 16 + lr;
                        int c = (kk * 32 + lq * 8) ^ ((r & 7) << 3);
                        bf16x8 bk = *reinterpret_cast<const bf16x8*>(&Ks[cur][r * 128 + c]);
                        s0[jt] = MFMA16(bk, qf0, s0[jt]);
                        s1[jt] = MFMA16(bk, qf1, s1[jt]);
                    }
                }
                __builtin_amdgcn_s_setprio(0);
                // ---- sliding-window masks (exact per-element test) ----
                if (mwin || mdia) {
                    int qi0 = row0 + (2 * pp) * 16 + lr;
                    int qi1 = row0 + (2 * pp + 1) * 16 + lr;
#pragma unroll
                    for (int jt = 0; jt < 4; ++jt)
#pragma unroll
                        for (int j = 0; j < 4; ++j) {
                            int kj = j0 + jt * 16 + lq * 4 + j;
                            if (!(kj <= qi0 && kj > qi0 - 1024)) s0[jt][j] = -1e30f;
                            if (!(kj <= qi1 && kj > qi1 - 1024)) s1[jt][j] = -1e30f;
                        }
                }
                // ---- fixed-shift softmax + in-register bf16 pack ----
#pragma unroll
                for (int jt = 0; jt < 4; ++jt)
#pragma unroll
                    for (int hh = 0; hh < 2; ++hh) {
                        float p0 = exp2f(s0[jt][2 * hh] - 11.5415603f);
                        float p1 = exp2f(s0[jt][2 * hh + 1] - 11.5415603f);
                        lsum[2 * pp] += p0 + p1;
                        asm("v_cvt_pk_bf16_f32 %0, %1, %2"
                            : "=v"(pk[2 * pp][jt][hh]) : "v"(p0), "v"(p1));
                        float q0 = exp2f(s1[jt][2 * hh] - 11.5415603f);
                        float q1 = exp2f(s1[jt][2 * hh + 1] - 11.5415603f);
                        lsum[2 * pp + 1] += q0 + q1;
                        asm("v_cvt_pk_bf16_f32 %0, %1, %2"
                            : "=v"(pk[2 * pp + 1][jt][hh]) : "v"(q0), "v"(q1));
                    }
            }
            // ---- O += P V: each V fragment shared by all 4 groups ----
            __builtin_amdgcn_s_setprio(1);
#pragma unroll
            for (int kk2 = 0; kk2 < 2; ++kk2) {
                union { unsigned u[4]; bf16x8 v; } pu[4];
#pragma unroll
                for (int gg = 0; gg < 4; ++gg) {
                    pu[gg].u[0] = pk[gg][2 * kk2][0];
                    pu[gg].u[1] = pk[gg][2 * kk2][1];
                    pu[gg].u[2] = pk[gg][2 * kk2 + 1][0];
                    pu[gg].u[3] = pk[gg][2 * kk2 + 1][1];
                }
#pragma unroll
                for (int dt = 0; dt < 8; ++dt) {
                    int r = dt * 16 + lr;
                    int c = (kk2 * 32 + lq * 8) ^ ((r & 7) << 3);
                    bf16x8 bv = *reinterpret_cast<const bf16x8*>(&Vs[cur][r * 64 + c]);
#pragma unroll
                    for (int gg = 0; gg < 4; ++gg)
                        o[gg][dt] = MFMA16(pu[gg].v, bv, o[gg][dt]);
                }
            }
            __builtin_amdgcn_s_setprio(0);
        }
        __builtin_amdgcn_s_barrier();            // all waves done reading cur
        cur ^= 1;
    }
    // ---- final row-sum reduce + epilogue per group ----
#pragma unroll
    for (int gg = 0; gg < 4; ++gg) {
        float lt = lsum[gg];
        lt += __shfl_xor(lt, 16, 64);
        lt += __shfl_xor(lt, 32, 64);
        float li = 1.0f / lt;
        float lv[4];
#pragma unroll
        for (int j = 0; j < 4; ++j) lv[j] = __shfl(li, lq * 4 + j, 64);
#pragma unroll
        for (int dt = 0; dt < 8; ++dt)
#pragma unroll
            for (int j = 0; j < 4; ++j) {
                size_t base = (size_t)(b * 4096 + row0 + gg * 16 + lq * 4 + j) * 2048
                              + h * 128 + dt * 16 + lr;
                ao[base] = __float2bfloat16(o[gg][dt][j] * lv[j]);
            }
    }
}

extern "C" void kernel_launch(void* const* d_in, const int* in_sizes, int n_in,
                              void* d_out, int out_size, void* d_ws, size_t ws_size,
                              hipStream_t stream) {
    const float* x    = (const float*)d_in[0];
    const float* cosT = (const float*)d_in[1];
    const float* sinT = (const float*)d_in[2];
    const float* Wq   = (const float*)d_in[3];
    const float* Wk   = (const float*)d_in[4];
    const float* Wv   = (const float*)d_in[5];
    const float* Wo   = (const float*)d_in[6];
    const float* qnw  = (const float*)d_in[7];
    const float* knw  = (const float*)d_in[8];

    char* ws = (char*)d_ws;
    bf16* xb    = (bf16*)(ws);                 // 33,554,432 B  [8192][2048]
    bf16* wqkvT = (bf16*)(ws + 33554432);      // 12,582,912 B  [3072][2048]
    bf16* woT   = (bf16*)(ws + 46137344);      //  8,388,608 B  [2048][2048]
    bf16* qh    = (bf16*)(ws + 54525952);      // 33,554,432 B  [2][16][4096][128]
    bf16* kh    = (bf16*)(ws + 88080384);      //  8,388,608 B  [2][4][4096][128]
    bf16* vt    = (bf16*)(ws + 96468992);      //  8,388,608 B  [2][4][128][4096] -> total 100 MiB
    bf16* ao    = xb;                          // alias: xb dead after GEMM1
    bf16* qkv   = (bf16*)d_out;                // d_out as scratch: overwritten by GEMM2

    cvt_bf16_kernel<<<8192, 256, 0, stream>>>(x, xb, 16777216);
    transpose_wqkv_kernel<<<dim3(64, 96), 256, 0, stream>>>(Wq, Wk, Wv, wqkvT);
    transpose_w_kernel<<<dim3(64, 64), 256, 0, stream>>>(Wo, woT);
    // GEMM1: 256x192 tiles -> 512 blocks = exactly 2 rounds (R6-measured best)
    gemm8p_kernel<3, false><<<512, 512, 0, stream>>>(xb, wqkvT, (void*)qkv, 8192, 3072, 2048, 16);
    normrope_kernel<<<40960, 256, 0, stream>>>(qkv, cosT, sinT, qnw, knw, qh, kh);
    vtrans_kernel<<<dim3(64, 8), 256, 0, stream>>>(qkv, vt);
    attn_kernel<<<512, 256, 0, stream>>>(qh, kh, vt, ao);
    // GEMM2: 256x256 tiles -> 256 blocks = exactly 1 round
    gemm8p_kernel<4, true><<<256, 512, 0, stream>>>(ao, woT, d_out, 8192, 2048, 2048, 8);
}

// Round 13
// 351.069 us; speedup vs baseline: 1.3519x; 1.3519x over previous
//
#include <hip/hip_runtime.h>
#include <hip/hip_bf16.h>

typedef __hip_bfloat16 bf16;
typedef __attribute__((ext_vector_type(8))) __bf16 bf16x8;
typedef __attribute__((ext_vector_type(4))) float f32x4;

#define MFMA16(a, b, c) __builtin_amdgcn_mfma_f32_16x16x32_bf16((a), (b), (c), 0, 0, 0)

static __device__ __forceinline__ void gload_lds16(const void* g, void* l) {
    typedef const __attribute__((address_space(1))) unsigned gq_t;
    typedef __attribute__((address_space(3))) unsigned ls_t;
    __builtin_amdgcn_global_load_lds((gq_t*)g, (ls_t*)l, 16, 0, 0);
}

static __device__ __forceinline__ unsigned short f2bfbits(float f) {
    bf16 h = __float2bfloat16(f);
    return *reinterpret_cast<unsigned short*>(&h);
}

// ---------------- prepass: f32 -> bf16 cast of x ----------------
__global__ __launch_bounds__(256) void cvt_bf16_kernel(const float* __restrict__ in,
                                                       bf16* __restrict__ out, int n) {
    int i = (blockIdx.x * 256 + threadIdx.x) * 8;
    if (i < n) {
        float4 a = *reinterpret_cast<const float4*>(in + i);
        float4 b = *reinterpret_cast<const float4*>(in + i + 4);
        bf16 tmp[8];
        tmp[0] = __float2bfloat16(a.x); tmp[1] = __float2bfloat16(a.y);
        tmp[2] = __float2bfloat16(a.z); tmp[3] = __float2bfloat16(a.w);
        tmp[4] = __float2bfloat16(b.x); tmp[5] = __float2bfloat16(b.y);
        tmp[6] = __float2bfloat16(b.z); tmp[7] = __float2bfloat16(b.w);
        *reinterpret_cast<uint4*>(out + i) = *reinterpret_cast<const uint4*>(tmp);
    }
}

// ---------------- prepass: transpose Wq|Wk|Wv -> [3072][2048] bf16 ----------------
__global__ __launch_bounds__(256) void transpose_wqkv_kernel(const float* __restrict__ Wq,
                                                             const float* __restrict__ Wk,
                                                             const float* __restrict__ Wv,
                                                             bf16* __restrict__ out) {
    __shared__ float tile[32][33];
    int k0 = blockIdx.x * 32;   // along K (2048)
    int n0 = blockIdx.y * 32;   // along N (3072)
    int tx = threadIdx.x & 31, ty = threadIdx.x >> 5;  // 32 x 8
#pragma unroll
    for (int i = 0; i < 4; ++i) {
        int k = k0 + ty + i * 8, n = n0 + tx;
        float v;
        if (n < 2048)      v = Wq[(size_t)k * 2048 + n];
        else if (n < 2560) v = Wk[(size_t)k * 512 + (n - 2048)];
        else               v = Wv[(size_t)k * 512 + (n - 2560)];
        tile[ty + i * 8][tx] = v;
    }
    __syncthreads();
#pragma unroll
    for (int i = 0; i < 4; ++i)
        out[(size_t)(n0 + ty + i * 8) * 2048 + k0 + tx] = __float2bfloat16(tile[tx][ty + i * 8]);
}

// ---------------- prepass: transpose square W (2048x2048) -> bf16 ----------------
__global__ __launch_bounds__(256) void transpose_w_kernel(const float* __restrict__ in,
                                                          bf16* __restrict__ out) {
    __shared__ float tile[32][33];
    int k0 = blockIdx.x * 32, n0 = blockIdx.y * 32;
    int tx = threadIdx.x & 31, ty = threadIdx.x >> 5;
#pragma unroll
    for (int i = 0; i < 4; ++i)
        tile[ty + i * 8][tx] = in[(size_t)(k0 + ty + i * 8) * 2048 + n0 + tx];
    __syncthreads();
#pragma unroll
    for (int i = 0; i < 4; ++i)
        out[(size_t)(n0 + ty + i * 8) * 2048 + k0 + tx] = __float2bfloat16(tile[tx][ty + i * 8]);
}

// ---------------- 8-phase GEMM template (R6-verified best): C = A[M,K] @ BT[N,K]^T ----
template <int NFRAG, bool OUT_F32>
__global__ __launch_bounds__(512, 2) void gemm8p_kernel(const bf16* __restrict__ A,
                                                        const bf16* __restrict__ BT,
                                                        void* __restrict__ Cv,
                                                        int M, int N, int K, int nbn) {
    constexpr int BN = NFRAG * 64;
    constexpr int PB = NFRAG;          // B pieces per K-tile (1 gload/thread each)
    __shared__ bf16 As[2][256 * 64];
    __shared__ bf16 Bs[2][BN * 64];
    int t = threadIdx.x;
    int lane = t & 63, w = t >> 6;
    int wm = w >> 2, wn = w & 3;
    int lr = lane & 15, lq = lane >> 4;
    int lin = blockIdx.x;
    int cpx = gridDim.x >> 3;          // bijective XCD-chunked swizzle (grid % 8 == 0)
    int wg = (lin & 7) * cpx + (lin >> 3);
    int bm = wg / nbn, bn = wg % nbn;
    const bf16* Ab = A + (size_t)bm * 256 * K;
    const bf16* Bb = BT + (size_t)bn * BN * K;

    auto stA = [&](int slot, int kt, int piece) {
        int idx = piece * 512 + t;
        int r = idx >> 3, c8 = idx & 7;
        gload_lds16(Ab + (size_t)r * K + kt * 64 + ((c8 ^ (r & 7)) * 8), &As[slot][idx * 8]);
    };
    auto stB = [&](int slot, int kt, int piece) {
        int idx = piece * 512 + t;
        int r = idx >> 3, c8 = idx & 7;
        gload_lds16(Bb + (size_t)r * K + kt * 64 + ((c8 ^ (r & 7)) * 8), &Bs[slot][idx * 8]);
    };

    f32x4 acc[8][NFRAG] = {};
    bf16x8 bq[NFRAG][2], af[2][2];

    auto readB = [&](int slot) {
#pragma unroll
        for (int n = 0; n < NFRAG; ++n)
#pragma unroll
            for (int ks = 0; ks < 2; ++ks) {
                int ro = wn * (NFRAG * 16) + n * 16 + lr;
                int ch = (ks * 4 + lq) ^ (ro & 7);
                bq[n][ks] = *reinterpret_cast<const bf16x8*>(&Bs[slot][ro * 64 + ch * 8]);
            }
    };
    auto readA = [&](int mbase, int slot) {
#pragma unroll
        for (int mi = 0; mi < 2; ++mi)
#pragma unroll
            for (int ks = 0; ks < 2; ++ks) {
                int ro = wm * 128 + (mbase + mi) * 16 + lr;
                int ch = (ks * 4 + lq) ^ (ro & 7);
                af[mi][ks] = *reinterpret_cast<const bf16x8*>(&As[slot][ro * 64 + ch * 8]);
            }
    };
    auto mf = [&](int mbase) {
#pragma unroll
        for (int mi = 0; mi < 2; ++mi)
#pragma unroll
            for (int n = 0; n < NFRAG; ++n)
#pragma unroll
                for (int ks = 0; ks < 2; ++ks)
                    acc[mbase + mi][n] = MFMA16(af[mi][ks], bq[n][ks], acc[mbase + mi][n]);
    };

#define GATE_PB()                                                          \
    do {                                                                   \
        if constexpr (NFRAG == 4) asm volatile("s_waitcnt vmcnt(4)" ::: "memory"); \
        else                      asm volatile("s_waitcnt vmcnt(3)" ::: "memory"); \
    } while (0)
#define PHASE_TAIL()                                                       \
    do {                                                                   \
        __builtin_amdgcn_s_barrier();                                      \
        asm volatile("s_waitcnt lgkmcnt(0)" ::: "memory");                 \
    } while (0)
#define MFMA_CLUSTER(mb)                                                   \
    do {                                                                   \
        __builtin_amdgcn_s_setprio(1);                                     \
        mf(mb);                                                            \
        __builtin_amdgcn_s_setprio(0);                                     \
        __builtin_amdgcn_s_barrier();                                      \
    } while (0)

    int nkt = K >> 6;
#pragma unroll
    for (int p = 0; p < 4; ++p) stA(0, 0, p);
#pragma unroll
    for (int p = 0; p < PB; ++p) stB(0, 0, p);
#pragma unroll
    for (int p = 0; p < PB; ++p) stB(1, 1, p);
    GATE_PB();
    __builtin_amdgcn_s_barrier();

    int nI = nkt >> 1;
    for (int I = 0; I < nI; ++I) {
        int T = I << 1;
        bool s2 = (T + 2) < nkt, s3 = (T + 3) < nkt;
        readB(0); readA(0, 0);
#pragma unroll
        for (int p = 0; p < 4; ++p) stA(1, T + 1, p);
        PHASE_TAIL();
        MFMA_CLUSTER(0);
        readA(2, 0);
        if (s2) { stB(0, T + 2, 0); stB(0, T + 2, 1); }
        PHASE_TAIL();
        MFMA_CLUSTER(2);
        readA(4, 0);
        if (s2) {
#pragma unroll
            for (int p = 2; p < PB; ++p) stB(0, T + 2, p);
        }
        PHASE_TAIL();
        MFMA_CLUSTER(4);
        readA(6, 0);
        if (s2) GATE_PB();
        else    asm volatile("s_waitcnt vmcnt(0)" ::: "memory");
        PHASE_TAIL();
        MFMA_CLUSTER(6);
        readB(1); readA(0, 1);
        if (s2) {
#pragma unroll
            for (int p = 0; p < 4; ++p) stA(0, T + 2, p);
        }
        PHASE_TAIL();
        MFMA_CLUSTER(0);
        readA(2, 1);
        if (s3) { stB(1, T + 3, 0); stB(1, T + 3, 1); }
        PHASE_TAIL();
        MFMA_CLUSTER(2);
        readA(4, 1);
        if (s3) {
#pragma unroll
            for (int p = 2; p < PB; ++p) stB(1, T + 3, p);
        }
        PHASE_TAIL();
        MFMA_CLUSTER(4);
        readA(6, 1);
        if (s3) GATE_PB();
        else    asm volatile("s_waitcnt vmcnt(0)" ::: "memory");
        PHASE_TAIL();
        MFMA_CLUSTER(6);
    }
#undef GATE_PB
#undef PHASE_TAIL
#undef MFMA_CLUSTER

#pragma unroll
    for (int m = 0; m < 8; ++m)
#pragma unroll
        for (int n = 0; n < NFRAG; ++n) {
            int row = bm * 256 + wm * 128 + m * 16 + lq * 4;
            int col = bn * BN + wn * (NFRAG * 16) + n * 16 + lr;
#pragma unroll
            for (int j = 0; j < 4; ++j) {
                if (OUT_F32)
                    ((float*)Cv)[(size_t)(row + j) * N + col] = acc[m][n][j];
                else
                    ((bf16*)Cv)[(size_t)(row + j) * N + col] = __float2bfloat16(acc[m][n][j]);
            }
        }
}

// ---------------- RMSNorm + RoPE for Q and K only (V handled by vtrans) ----------------
__global__ __launch_bounds__(256) void normrope_kernel(const bf16* __restrict__ qkv,
                                                       const float* __restrict__ cosT,
                                                       const float* __restrict__ sinT,
                                                       const float* __restrict__ qnw,
                                                       const float* __restrict__ knw,
                                                       bf16* __restrict__ qh,
                                                       bf16* __restrict__ kh) {
    int t = threadIdx.x;
    int lane = t & 63, wv = t >> 6;
    int blk = blockIdx.x;
    int r = blk / 5;
    int s = (blk % 5) * 4 + wv;     // slot 0..19: 0-15 Q heads, 16-19 K groups
    int b = r >> 12, l = r & 4095;
    int e0 = lane * 2;
    const bf16* src = qkv + (size_t)r * 3072 + s * 128;
    ushort2 xu = *reinterpret_cast<const ushort2*>(src + e0);
    float v0 = __uint_as_float((unsigned)xu.x << 16);
    float v1 = __uint_as_float((unsigned)xu.y << 16);
    float ss = v0 * v0 + v1 * v1;
#pragma unroll
    for (int d = 1; d < 64; d <<= 1) ss += __shfl_xor(ss, d, 64);
    float rn = rsqrtf(ss * (1.0f / 128.0f) + 1e-6f);
    const float* wn = (s < 16) ? qnw : knw;
    float2 wv2 = *reinterpret_cast<const float2*>(wn + e0);
    float xn0 = v0 * rn * wv2.x;
    float xn1 = v1 * rn * wv2.y;
    float xp0 = __shfl_xor(xn0, 32, 64);
    float xp1 = __shfl_xor(xn1, 32, 64);
    float r0 = (lane < 32) ? -xp0 : xp0;
    float r1 = (lane < 32) ? -xp1 : xp1;
    float2 c2 = *reinterpret_cast<const float2*>(cosT + (size_t)l * 128 + e0);
    float2 s2 = *reinterpret_cast<const float2*>(sinT + (size_t)l * 128 + e0);
    float o0 = xn0 * c2.x + r0 * s2.x;
    float o1 = xn1 * c2.y + r1 * s2.y;
    ushort2 ou;
    if (s < 16) {
        const float scl = 0.0625f * 1.44269504088896f;  // SCALE * log2(e) folded into q
        ou.x = f2bfbits(o0 * scl);
        ou.y = f2bfbits(o1 * scl);
        bf16* dst = qh + ((size_t)(b * 16 + s) * 4096 + l) * 128;
        *reinterpret_cast<ushort2*>(dst + e0) = ou;
    } else {
        int g = s - 16;
        ou.x = f2bfbits(o0);
        ou.y = f2bfbits(o1);
        int sw = (l & 7) << 3;   // bits >=3: pair adjacency + 4B alignment preserved
        bf16* dst = kh + ((size_t)(b * 4 + g) * 4096 + l) * 128;
        *reinterpret_cast<ushort2*>(dst + (e0 ^ sw)) = ou;
    }
}

// ---------------- V transpose via LDS (coalesced both sides) ----------------
__global__ __launch_bounds__(256) void vtrans_kernel(const bf16* __restrict__ qkv,
                                                     bf16* __restrict__ vt) {
    __shared__ bf16 tile[64][132];   // pad 4 elems: row stride 264 B
    int t = threadIdx.x;
    int l0 = blockIdx.x * 64;
    int bg = blockIdx.y;             // b*4+g
    int b = bg >> 2, g = bg & 3;
    const bf16* src = qkv + ((size_t)(b * 4096 + l0)) * 3072 + 2560 + g * 128;
#pragma unroll
    for (int i = 0; i < 4; ++i) {
        int c = i * 256 + t;
        int r = c >> 4, c16 = c & 15;
        uint4 v = *reinterpret_cast<const uint4*>(src + (size_t)r * 3072 + c16 * 8);
        *reinterpret_cast<uint2*>(&tile[r][c16 * 8]) = make_uint2(v.x, v.y);
        *reinterpret_cast<uint2*>(&tile[r][c16 * 8 + 4]) = make_uint2(v.z, v.w);
    }
    __syncthreads();
    bf16* dst = vt + (size_t)bg * 128 * 4096 + l0;
    int cj = t & 63;
    int pos = (cj & 0x23) | ((cj & 16) >> 2) | ((cj & 12) << 1);  // sigma(cj)
#pragma unroll
    for (int dd = 0; dd < 32; ++dd) {
        int d = (t >> 6) * 32 + dd;
        dst[(size_t)d * 4096 + (pos ^ ((d & 7) << 3))] = tile[cj][d];
    }
}

// ---------------- sliding-window flash attention (bf16, R11-verified best) ----------------
__global__ __launch_bounds__(512, 2) void attn_kernel(const bf16* __restrict__ qh,
                                                      const bf16* __restrict__ kh,
                                                      const bf16* __restrict__ vt,
                                                      bf16* __restrict__ ao) {
    __shared__ bf16 Ks[2][64 * 128];    // 32 KiB
    __shared__ bf16 Vs[2][128 * 64];    // 32 KiB -> 64 KiB total
    int t = threadIdx.x;
    int lane = t & 63, w = t >> 6;
    int lr = lane & 15, lq = lane >> 4;
    int bid = blockIdx.x;
    int bh = (bid & 7) * 4 + (bid >> 7);     // XCD-resident K/V mapping (bijective, 512 blocks)
    int qs = ((bid >> 3) & 15) * 256;
    int b = bh >> 4, h = bh & 15, g = h >> 2;
    int row0 = qs + w * 32;
    const bf16* qp = qh + ((size_t)(b * 16 + h) * 4096 + row0) * 128;
    const bf16* kp = kh + (size_t)(b * 4 + g) * 4096 * 128;
    const bf16* vp = vt + (size_t)(b * 4 + g) * 128 * 4096;

    bf16x8 aq[2][4];
#pragma unroll
    for (int g2 = 0; g2 < 2; ++g2)
#pragma unroll
        for (int kk = 0; kk < 4; ++kk)
            aq[g2][kk] = *reinterpret_cast<const bf16x8*>(qp + (size_t)(g2 * 16 + lr) * 128 + kk * 32 + lq * 8);

    f32x4 o0[8] = {}, o1[8] = {};
    float lsum0 = 0.f, lsum1 = 0.f;
    int qi0 = row0 + lr, qi1 = row0 + 16 + lr;
    int sA = max(0, row0 - 1023) >> 6;
    int sB = max(0, row0 + 16 - 1023) >> 6;
    int t1w = row0 >> 6;
    int t0w = sA;
    int t0 = max(0, qs - 1023) >> 6;
    int t1 = (qs + 255) >> 6;

    auto stage = [&](int buf, int kt) {
        int j0 = kt * 64;
        const bf16* kg = kp + (size_t)j0 * 128;
#pragma unroll
        for (int i = 0; i < 2; ++i) {
            int c = i * 512 + t;
            gload_lds16(kg + c * 8, &Ks[buf][c * 8]);
        }
#pragma unroll
        for (int i = 0; i < 2; ++i) {
            int c = i * 512 + t;
            int d = c >> 3, co = (c & 7) * 8;
            gload_lds16(vp + (size_t)d * 4096 + j0 + co, &Vs[buf][c * 8]);
        }
    };

    stage(0, t0);
    int cur = 0;

    for (int kt = t0; kt <= t1; ++kt) {
        if (kt < t1) {
            stage(cur ^ 1, kt + 1);
            asm volatile("s_waitcnt vmcnt(4)" ::: "memory");
        } else {
            asm volatile("s_waitcnt vmcnt(0)" ::: "memory");
        }
        __builtin_amdgcn_s_barrier();
        if (kt >= t0w && kt <= t1w) {
            int j0 = kt * 64;
            f32x4 s0[4] = {}, s1[4] = {};
            __builtin_amdgcn_s_setprio(1);
#pragma unroll
            for (int jt = 0; jt < 4; ++jt) {
                int r = jt * 16 + lr;
                int rs = (r & 7) << 3;
#pragma unroll
                for (int kk = 0; kk < 4; ++kk) {
                    int c = kk * 32 + lq * 8;
                    bf16x8 bk = *reinterpret_cast<const bf16x8*>(&Ks[cur][r * 128 + (c ^ rs)]);
                    s0[jt] = MFMA16(bk, aq[0][kk], s0[jt]);
                    s1[jt] = MFMA16(bk, aq[1][kk], s1[jt]);
                }
            }
            __builtin_amdgcn_s_setprio(0);
            if (kt <= sA + 1 || kt == t1w) {
#pragma unroll
                for (int jt = 0; jt < 4; ++jt)
#pragma unroll
                    for (int j = 0; j < 4; ++j) {
                        int kj = j0 + jt * 16 + lq * 4 + j;
                        if (!(kj <= qi0 && kj > qi0 - 1024)) s0[jt][j] = -1e30f;
                    }
            }
            if (kt <= sB + 1 || kt == t1w) {
#pragma unroll
                for (int jt = 0; jt < 4; ++jt)
#pragma unroll
                    for (int j = 0; j < 4; ++j) {
                        int kj = j0 + jt * 16 + lq * 4 + j;
                        if (!(kj <= qi1 && kj > qi1 - 1024)) s1[jt][j] = -1e30f;
                    }
            }
            unsigned pk0[4][2], pk1[4][2];
#pragma unroll
            for (int jt = 0; jt < 4; ++jt)
#pragma unroll
                for (int hh = 0; hh < 2; ++hh) {
                    float p0 = exp2f(s0[jt][2 * hh] - 11.5415603f);
                    float p1 = exp2f(s0[jt][2 * hh + 1] - 11.5415603f);
                    lsum0 += p0 + p1;
                    asm("v_cvt_pk_bf16_f32 %0, %1, %2" : "=v"(pk0[jt][hh]) : "v"(p0), "v"(p1));
                }
#pragma unroll
            for (int jt = 0; jt < 4; ++jt)
#pragma unroll
                for (int hh = 0; hh < 2; ++hh) {
                    float p0 = exp2f(s1[jt][2 * hh] - 11.5415603f);
                    float p1 = exp2f(s1[jt][2 * hh + 1] - 11.5415603f);
                    lsum1 += p0 + p1;
                    asm("v_cvt_pk_bf16_f32 %0, %1, %2" : "=v"(pk1[jt][hh]) : "v"(p0), "v"(p1));
                }
            __builtin_amdgcn_s_setprio(1);
#pragma unroll
            for (int kk2 = 0; kk2 < 2; ++kk2) {
                union { unsigned u[4]; bf16x8 v; } pu0, pu1;
                pu0.u[0] = pk0[2 * kk2][0]; pu0.u[1] = pk0[2 * kk2][1];
                pu0.u[2] = pk0[2 * kk2 + 1][0]; pu0.u[3] = pk0[2 * kk2 + 1][1];
                pu1.u[0] = pk1[2 * kk2][0]; pu1.u[1] = pk1[2 * kk2][1];
                pu1.u[2] = pk1[2 * kk2 + 1][0]; pu1.u[3] = pk1[2 * kk2 + 1][1];
#pragma unroll
                for (int dt = 0; dt < 8; ++dt) {
                    int r = dt * 16 + lr;
                    int c = kk2 * 32 + lq * 8;
                    bf16x8 bv = *reinterpret_cast<const bf16x8*>(&Vs[cur][r * 64 + (c ^ ((r & 7) << 3))]);
                    o0[dt] = MFMA16(pu0.v, bv, o0[dt]);
                    o1[dt] = MFMA16(pu1.v, bv, o1[dt]);
                }
            }
            __builtin_amdgcn_s_setprio(0);
        }
        __builtin_amdgcn_s_barrier();
        cur ^= 1;
    }
    float lt0 = lsum0, lt1 = lsum1;
    lt0 += __shfl_xor(lt0, 16, 64);  lt0 += __shfl_xor(lt0, 32, 64);
    lt1 += __shfl_xor(lt1, 16, 64);  lt1 += __shfl_xor(lt1, 32, 64);
    float li0 = 1.0f / lt0, li1 = 1.0f / lt1;
    float lv0[4], lv1[4];
#pragma unroll
    for (int j = 0; j < 4; ++j) {
        lv0[j] = __shfl(li0, lq * 4 + j, 64);
        lv1[j] = __shfl(li1, lq * 4 + j, 64);
    }
#pragma unroll
    for (int dt = 0; dt < 8; ++dt)
#pragma unroll
        for (int j = 0; j < 4; ++j) {
            size_t base = (size_t)(b * 4096 + row0 + lq * 4 + j) * 2048 + h * 128 + dt * 16 + lr;
            ao[base] = __float2bfloat16(o0[dt][j] * lv0[j]);
            ao[base + (size_t)16 * 2048] = __float2bfloat16(o1[dt][j] * lv1[j]);
        }
}

extern "C" void kernel_launch(void* const* d_in, const int* in_sizes, int n_in,
                              void* d_out, int out_size, void* d_ws, size_t ws_size,
                              hipStream_t stream) {
    const float* x    = (const float*)d_in[0];
    const float* cosT = (const float*)d_in[1];
    const float* sinT = (const float*)d_in[2];
    const float* Wq   = (const float*)d_in[3];
    const float* Wk   = (const float*)d_in[4];
    const float* Wv   = (const float*)d_in[5];
    const float* Wo   = (const float*)d_in[6];
    const float* qnw  = (const float*)d_in[7];
    const float* knw  = (const float*)d_in[8];

    char* ws = (char*)d_ws;
    bf16* xb    = (bf16*)(ws);                 // 33,554,432 B  [8192][2048]
    bf16* wqkvT = (bf16*)(ws + 33554432);      // 12,582,912 B  [3072][2048]
    bf16* woT   = (bf16*)(ws + 46137344);      //  8,388,608 B  [2048][2048]
    bf16* qh    = (bf16*)(ws + 54525952);      // 33,554,432 B  [2][16][4096][128]
    bf16* kh    = (bf16*)(ws + 88080384);      //  8,388,608 B  [2][4][4096][128]
    bf16* vt    = (bf16*)(ws + 96468992);      //  8,388,608 B  [2][4][128][4096] -> total 100 MiB
    bf16* ao    = xb;                          // alias: xb dead after GEMM1
    bf16* qkv   = (bf16*)d_out;                // d_out as scratch: overwritten by GEMM2

    cvt_bf16_kernel<<<8192, 256, 0, stream>>>(x, xb, 16777216);
    transpose_wqkv_kernel<<<dim3(64, 96), 256, 0, stream>>>(Wq, Wk, Wv, wqkvT);
    transpose_w_kernel<<<dim3(64, 64), 256, 0, stream>>>(Wo, woT);
    // GEMM1: 256x192 tiles -> 512 blocks = exactly 2 rounds (R6-measured best)
    gemm8p_kernel<3, false><<<512, 512, 0, stream>>>(xb, wqkvT, (void*)qkv, 8192, 3072, 2048, 16);
    normrope_kernel<<<40960, 256, 0, stream>>>(qkv, cosT, sinT, qnw, knw, qh, kh);
    vtrans_kernel<<<dim3(64, 8), 256, 0, stream>>>(qkv, vt);
    attn_kernel<<<512, 512, 0, stream>>>(qh, kh, vt, ao);
    // GEMM2: 256x256 tiles -> 256 blocks = exactly 1 round
    gemm8p_kernel<4, true><<<256, 512, 0, stream>>>(ao, woT, d_out, 8192, 2048, 2048, 8);
}

// Round 14
// 342.005 us; speedup vs baseline: 1.3877x; 1.0265x over previous
//
#include <hip/hip_runtime.h>
#include <hip/hip_bf16.h>

typedef __hip_bfloat16 bf16;
typedef __attribute__((ext_vector_type(8))) __bf16 bf16x8;
typedef __attribute__((ext_vector_type(4))) float f32x4;

#define MFMA16(a, b, c) __builtin_amdgcn_mfma_f32_16x16x32_bf16((a), (b), (c), 0, 0, 0)

static __device__ __forceinline__ void gload_lds16(const void* g, void* l) {
    typedef const __attribute__((address_space(1))) unsigned gq_t;
    typedef __attribute__((address_space(3))) unsigned ls_t;
    __builtin_amdgcn_global_load_lds((gq_t*)g, (ls_t*)l, 16, 0, 0);
}

static __device__ __forceinline__ unsigned short f2bfbits(float f) {
    bf16 h = __float2bfloat16(f);
    return *reinterpret_cast<unsigned short*>(&h);
}

// ---------------- prepass: f32 -> bf16 cast of x ----------------
__global__ __launch_bounds__(256) void cvt_bf16_kernel(const float* __restrict__ in,
                                                       bf16* __restrict__ out, int n) {
    int i = (blockIdx.x * 256 + threadIdx.x) * 8;
    if (i < n) {
        float4 a = *reinterpret_cast<const float4*>(in + i);
        float4 b = *reinterpret_cast<const float4*>(in + i + 4);
        bf16 tmp[8];
        tmp[0] = __float2bfloat16(a.x); tmp[1] = __float2bfloat16(a.y);
        tmp[2] = __float2bfloat16(a.z); tmp[3] = __float2bfloat16(a.w);
        tmp[4] = __float2bfloat16(b.x); tmp[5] = __float2bfloat16(b.y);
        tmp[6] = __float2bfloat16(b.z); tmp[7] = __float2bfloat16(b.w);
        *reinterpret_cast<uint4*>(out + i) = *reinterpret_cast<const uint4*>(tmp);
    }
}

// ---------------- prepass: transpose Wq|Wk|Wv -> [3072][2048] bf16 ----------------
__global__ __launch_bounds__(256) void transpose_wqkv_kernel(const float* __restrict__ Wq,
                                                             const float* __restrict__ Wk,
                                                             const float* __restrict__ Wv,
                                                             bf16* __restrict__ out) {
    __shared__ float tile[32][33];
    int k0 = blockIdx.x * 32;   // along K (2048)
    int n0 = blockIdx.y * 32;   // along N (3072)
    int tx = threadIdx.x & 31, ty = threadIdx.x >> 5;  // 32 x 8
#pragma unroll
    for (int i = 0; i < 4; ++i) {
        int k = k0 + ty + i * 8, n = n0 + tx;
        float v;
        if (n < 2048)      v = Wq[(size_t)k * 2048 + n];
        else if (n < 2560) v = Wk[(size_t)k * 512 + (n - 2048)];
        else               v = Wv[(size_t)k * 512 + (n - 2560)];
        tile[ty + i * 8][tx] = v;
    }
    __syncthreads();
#pragma unroll
    for (int i = 0; i < 4; ++i)
        out[(size_t)(n0 + ty + i * 8) * 2048 + k0 + tx] = __float2bfloat16(tile[tx][ty + i * 8]);
}

// ---------------- prepass: transpose square W (2048x2048) -> bf16 ----------------
__global__ __launch_bounds__(256) void transpose_w_kernel(const float* __restrict__ in,
                                                          bf16* __restrict__ out) {
    __shared__ float tile[32][33];
    int k0 = blockIdx.x * 32, n0 = blockIdx.y * 32;
    int tx = threadIdx.x & 31, ty = threadIdx.x >> 5;
#pragma unroll
    for (int i = 0; i < 4; ++i)
        tile[ty + i * 8][tx] = in[(size_t)(k0 + ty + i * 8) * 2048 + n0 + tx];
    __syncthreads();
#pragma unroll
    for (int i = 0; i < 4; ++i)
        out[(size_t)(n0 + ty + i * 8) * 2048 + k0 + tx] = __float2bfloat16(tile[tx][ty + i * 8]);
}

// ---------------- occupancy-GEMM: 128 x (NFRAG*64) tile, 2 blocks/CU ----------------
// 8 waves (2M x 4N), per-wave C = 64 x NFRAG*16, BK=64. LDS = 32 + NFRAG*16 KiB
// (NFRAG=3: 80 KiB, NFRAG=2: 64 KiB) -> 2 blocks/CU = 16 waves/CU (vs gemm8p's 8).
// Same verified slot/gate discipline compressed to 4 phases per 2 K-tiles:
//   ph1: readB(s0)+readA(m01,s0); stage A(T+1)->s1          ; TAIL; 12 MFMA
//   ph2: readA(m23,s0);           stage B(T+2)->s0; GATE(PB); TAIL; 12 MFMA
//   ph3: readB(s1)+readA(m01,s1); stage A(T+2)->s0          ; TAIL; 12 MFMA
//   ph4: readA(m23,s1);           stage B(T+3)->s1; GATE(PB); TAIL; 12 MFMA
// GATE leaves exactly the PB just-issued B loads in flight (certifies prior tile).
// Staging into a slot only after the exit barrier of its last reader (safe).
template <int NFRAG, bool OUT_F32>
__global__ __launch_bounds__(512, 4) void gemmocc_kernel(const bf16* __restrict__ A,
                                                         const bf16* __restrict__ BT,
                                                         void* __restrict__ Cv,
                                                         int M, int N, int K, int nbn) {
    constexpr int BN = NFRAG * 64;
    constexpr int PB = NFRAG;          // B pieces per K-tile (1 gload/thread each)
    __shared__ bf16 As[2][128 * 64];   // 16 KiB per slot
    __shared__ bf16 Bs[2][BN * 64];
    int t = threadIdx.x;
    int lane = t & 63, w = t >> 6;
    int wm = w >> 2, wn = w & 3;       // 2 x 4 wave grid; per-wave C = 64 x NFRAG*16
    int lr = lane & 15, lq = lane >> 4;
    int lin = blockIdx.x;
    int cpx = gridDim.x >> 3;          // bijective XCD-chunked swizzle (grid % 8 == 0)
    int wg = (lin & 7) * cpx + (lin >> 3);
    int bm = wg / nbn, bn = wg % nbn;
    const bf16* Ab = A + (size_t)bm * 128 * K;
    const bf16* Bb = BT + (size_t)bn * BN * K;

    auto stA = [&](int slot, int kt, int piece) {
        int idx = piece * 512 + t;         // 0..1023 16B chunks (128 rows x 8)
        int r = idx >> 3, c8 = idx & 7;
        gload_lds16(Ab + (size_t)r * K + kt * 64 + ((c8 ^ (r & 7)) * 8), &As[slot][idx * 8]);
    };
    auto stB = [&](int slot, int kt, int piece) {
        int idx = piece * 512 + t;         // 0..BN*8-1
        int r = idx >> 3, c8 = idx & 7;
        gload_lds16(Bb + (size_t)r * K + kt * 64 + ((c8 ^ (r & 7)) * 8), &Bs[slot][idx * 8]);
    };

    f32x4 acc[4][NFRAG] = {};
    bf16x8 bq[NFRAG][2], af[2][2];

    auto readB = [&](int slot) {
#pragma unroll
        for (int n = 0; n < NFRAG; ++n)
#pragma unroll
            for (int ks = 0; ks < 2; ++ks) {
                int ro = wn * (NFRAG * 16) + n * 16 + lr;
                int ch = (ks * 4 + lq) ^ (ro & 7);
                bq[n][ks] = *reinterpret_cast<const bf16x8*>(&Bs[slot][ro * 64 + ch * 8]);
            }
    };
    auto readA = [&](int mbase, int slot) {
#pragma unroll
        for (int mi = 0; mi < 2; ++mi)
#pragma unroll
            for (int ks = 0; ks < 2; ++ks) {
                int ro = wm * 64 + (mbase + mi) * 16 + lr;
                int ch = (ks * 4 + lq) ^ (ro & 7);
                af[mi][ks] = *reinterpret_cast<const bf16x8*>(&As[slot][ro * 64 + ch * 8]);
            }
    };
    auto mf = [&](int mbase) {
#pragma unroll
        for (int mi = 0; mi < 2; ++mi)
#pragma unroll
            for (int n = 0; n < NFRAG; ++n)
#pragma unroll
                for (int ks = 0; ks < 2; ++ks)
                    acc[mbase + mi][n] = MFMA16(af[mi][ks], bq[n][ks], acc[mbase + mi][n]);
    };

#define GATE_PB() asm volatile("s_waitcnt vmcnt(%0)" :: "i"(PB) : "memory")
#define PHASE_TAIL()                                                       \
    do {                                                                   \
        __builtin_amdgcn_s_barrier();                                      \
        asm volatile("s_waitcnt lgkmcnt(0)" ::: "memory");                 \
    } while (0)
#define MFMA_CLUSTER(mb)                                                   \
    do {                                                                   \
        __builtin_amdgcn_s_setprio(1);                                     \
        mf(mb);                                                            \
        __builtin_amdgcn_s_setprio(0);                                     \
        __builtin_amdgcn_s_barrier();                                      \
    } while (0)

    int nkt = K >> 6;   // even (K=2048 -> 32)
    // ---- prologue: A(0)->s0, B(0)->s0, B(1)->s1; certify tile 0 (B(1) stays in flight) ----
    stA(0, 0, 0); stA(0, 0, 1);
#pragma unroll
    for (int p = 0; p < PB; ++p) stB(0, 0, p);
#pragma unroll
    for (int p = 0; p < PB; ++p) stB(1, 1, p);
    GATE_PB();
    __builtin_amdgcn_s_barrier();

    int nI = nkt >> 1;
    for (int I = 0; I < nI; ++I) {
        int T = I << 1;
        bool s2 = (T + 2) < nkt;           // T+3 < nkt iff s2 (nkt even)
        // ---- ph1: tile T (s0), m0-1; stage A(T+1) -> s1 ----
        readB(0); readA(0, 0);
        stA(1, T + 1, 0); stA(1, T + 1, 1);
        PHASE_TAIL();
        MFMA_CLUSTER(0);
        // ---- ph2: m2-3; stage B(T+2) -> s0; GATE certifies T+1 ----
        readA(2, 0);
        if (s2) {
#pragma unroll
            for (int p = 0; p < PB; ++p) stB(0, T + 2, p);
            GATE_PB();
        } else {
            asm volatile("s_waitcnt vmcnt(0)" ::: "memory");
        }
        PHASE_TAIL();
        MFMA_CLUSTER(2);
        // ---- ph3: tile T+1 (s1), m0-1; stage A(T+2) -> s0 ----
        readB(1); readA(0, 1);
        if (s2) { stA(0, T + 2, 0); stA(0, T + 2, 1); }
        PHASE_TAIL();
        MFMA_CLUSTER(0);
        // ---- ph4: m2-3; stage B(T+3) -> s1; GATE certifies T+2 ----
        readA(2, 1);
        if (s2) {
#pragma unroll
            for (int p = 0; p < PB; ++p) stB(1, T + 3, p);
            GATE_PB();
        } else {
            asm volatile("s_waitcnt vmcnt(0)" ::: "memory");
        }
        PHASE_TAIL();
        MFMA_CLUSTER(2);
    }
#undef GATE_PB
#undef PHASE_TAIL
#undef MFMA_CLUSTER

    // ---- epilogue ----
#pragma unroll
    for (int m = 0; m < 4; ++m)
#pragma unroll
        for (int n = 0; n < NFRAG; ++n) {
            int row = bm * 128 + wm * 64 + m * 16 + lq * 4;
            int col = bn * BN + wn * (NFRAG * 16) + n * 16 + lr;
#pragma unroll
            for (int j = 0; j < 4; ++j) {
                if (OUT_F32)
                    ((float*)Cv)[(size_t)(row + j) * N + col] = acc[m][n][j];
                else
                    ((bf16*)Cv)[(size_t)(row + j) * N + col] = __float2bfloat16(acc[m][n][j]);
            }
        }
}

// ---------------- RMSNorm + RoPE for Q and K only (V handled by vtrans) ----------------
__global__ __launch_bounds__(256) void normrope_kernel(const bf16* __restrict__ qkv,
                                                       const float* __restrict__ cosT,
                                                       const float* __restrict__ sinT,
                                                       const float* __restrict__ qnw,
                                                       const float* __restrict__ knw,
                                                       bf16* __restrict__ qh,
                                                       bf16* __restrict__ kh) {
    int t = threadIdx.x;
    int lane = t & 63, wv = t >> 6;
    int blk = blockIdx.x;
    int r = blk / 5;
    int s = (blk % 5) * 4 + wv;     // slot 0..19: 0-15 Q heads, 16-19 K groups
    int b = r >> 12, l = r & 4095;
    int e0 = lane * 2;
    const bf16* src = qkv + (size_t)r * 3072 + s * 128;
    ushort2 xu = *reinterpret_cast<const ushort2*>(src + e0);
    float v0 = __uint_as_float((unsigned)xu.x << 16);
    float v1 = __uint_as_float((unsigned)xu.y << 16);
    float ss = v0 * v0 + v1 * v1;
#pragma unroll
    for (int d = 1; d < 64; d <<= 1) ss += __shfl_xor(ss, d, 64);
    float rn = rsqrtf(ss * (1.0f / 128.0f) + 1e-6f);
    const float* wn = (s < 16) ? qnw : knw;
    float2 wv2 = *reinterpret_cast<const float2*>(wn + e0);
    float xn0 = v0 * rn * wv2.x;
    float xn1 = v1 * rn * wv2.y;
    float xp0 = __shfl_xor(xn0, 32, 64);
    float xp1 = __shfl_xor(xn1, 32, 64);
    float r0 = (lane < 32) ? -xp0 : xp0;
    float r1 = (lane < 32) ? -xp1 : xp1;
    float2 c2 = *reinterpret_cast<const float2*>(cosT + (size_t)l * 128 + e0);
    float2 s2 = *reinterpret_cast<const float2*>(sinT + (size_t)l * 128 + e0);
    float o0 = xn0 * c2.x + r0 * s2.x;
    float o1 = xn1 * c2.y + r1 * s2.y;
    ushort2 ou;
    if (s < 16) {
        const float scl = 0.0625f * 1.44269504088896f;  // SCALE * log2(e) folded into q
        ou.x = f2bfbits(o0 * scl);
        ou.y = f2bfbits(o1 * scl);
        bf16* dst = qh + ((size_t)(b * 16 + s) * 4096 + l) * 128;
        *reinterpret_cast<ushort2*>(dst + e0) = ou;
    } else {
        int g = s - 16;
        ou.x = f2bfbits(o0);
        ou.y = f2bfbits(o1);
        int sw = (l & 7) << 3;   // bits >=3: pair adjacency + 4B alignment preserved
        bf16* dst = kh + ((size_t)(b * 4 + g) * 4096 + l) * 128;
        *reinterpret_cast<ushort2*>(dst + (e0 ^ sw)) = ou;
    }
}

// ---------------- V transpose via LDS (coalesced both sides) ----------------
__global__ __launch_bounds__(256) void vtrans_kernel(const bf16* __restrict__ qkv,
                                                     bf16* __restrict__ vt) {
    __shared__ bf16 tile[64][132];   // pad 4 elems: row stride 264 B
    int t = threadIdx.x;
    int l0 = blockIdx.x * 64;
    int bg = blockIdx.y;             // b*4+g
    int b = bg >> 2, g = bg & 3;
    const bf16* src = qkv + ((size_t)(b * 4096 + l0)) * 3072 + 2560 + g * 128;
#pragma unroll
    for (int i = 0; i < 4; ++i) {
        int c = i * 256 + t;
        int r = c >> 4, c16 = c & 15;
        uint4 v = *reinterpret_cast<const uint4*>(src + (size_t)r * 3072 + c16 * 8);
        *reinterpret_cast<uint2*>(&tile[r][c16 * 8]) = make_uint2(v.x, v.y);
        *reinterpret_cast<uint2*>(&tile[r][c16 * 8 + 4]) = make_uint2(v.z, v.w);
    }
    __syncthreads();
    bf16* dst = vt + (size_t)bg * 128 * 4096 + l0;
    int cj = t & 63;
    int pos = (cj & 0x23) | ((cj & 16) >> 2) | ((cj & 12) << 1);  // sigma(cj)
#pragma unroll
    for (int dd = 0; dd < 32; ++dd) {
        int d = (t >> 6) * 32 + dd;
        dst[(size_t)d * 4096 + (pos ^ ((d & 7) << 3))] = tile[cj][d];
    }
}

// ---------------- sliding-window flash attention (bf16, R11/R13-verified best) ----------------
__global__ __launch_bounds__(512, 2) void attn_kernel(const bf16* __restrict__ qh,
                                                      const bf16* __restrict__ kh,
                                                      const bf16* __restrict__ vt,
                                                      bf16* __restrict__ ao) {
    __shared__ bf16 Ks[2][64 * 128];    // 32 KiB
    __shared__ bf16 Vs[2][128 * 64];    // 32 KiB -> 64 KiB total
    int t = threadIdx.x;
    int lane = t & 63, w = t >> 6;
    int lr = lane & 15, lq = lane >> 4;
    int bid = blockIdx.x;
    int bh = (bid & 7) * 4 + (bid >> 7);     // XCD-resident K/V mapping (bijective, 512 blocks)
    int qs = ((bid >> 3) & 15) * 256;
    int b = bh >> 4, h = bh & 15, g = h >> 2;
    int row0 = qs + w * 32;
    const bf16* qp = qh + ((size_t)(b * 16 + h) * 4096 + row0) * 128;
    const bf16* kp = kh + (size_t)(b * 4 + g) * 4096 * 128;
    const bf16* vp = vt + (size_t)(b * 4 + g) * 128 * 4096;

    bf16x8 aq[2][4];
#pragma unroll
    for (int g2 = 0; g2 < 2; ++g2)
#pragma unroll
        for (int kk = 0; kk < 4; ++kk)
            aq[g2][kk] = *reinterpret_cast<const bf16x8*>(qp + (size_t)(g2 * 16 + lr) * 128 + kk * 32 + lq * 8);

    f32x4 o0[8] = {}, o1[8] = {};
    float lsum0 = 0.f, lsum1 = 0.f;
    int qi0 = row0 + lr, qi1 = row0 + 16 + lr;
    int sA = max(0, row0 - 1023) >> 6;
    int sB = max(0, row0 + 16 - 1023) >> 6;
    int t1w = row0 >> 6;
    int t0w = sA;
    int t0 = max(0, qs - 1023) >> 6;
    int t1 = (qs + 255) >> 6;

    auto stage = [&](int buf, int kt) {
        int j0 = kt * 64;
        const bf16* kg = kp + (size_t)j0 * 128;
#pragma unroll
        for (int i = 0; i < 2; ++i) {
            int c = i * 512 + t;
            gload_lds16(kg + c * 8, &Ks[buf][c * 8]);
        }
#pragma unroll
        for (int i = 0; i < 2; ++i) {
            int c = i * 512 + t;
            int d = c >> 3, co = (c & 7) * 8;
            gload_lds16(vp + (size_t)d * 4096 + j0 + co, &Vs[buf][c * 8]);
        }
    };

    stage(0, t0);
    int cur = 0;

    for (int kt = t0; kt <= t1; ++kt) {
        if (kt < t1) {
            stage(cur ^ 1, kt + 1);
            asm volatile("s_waitcnt vmcnt(4)" ::: "memory");
        } else {
            asm volatile("s_waitcnt vmcnt(0)" ::: "memory");
        }
        __builtin_amdgcn_s_barrier();
        if (kt >= t0w && kt <= t1w) {
            int j0 = kt * 64;
            f32x4 s0[4] = {}, s1[4] = {};
            __builtin_amdgcn_s_setprio(1);
#pragma unroll
            for (int jt = 0; jt < 4; ++jt) {
                int r = jt * 16 + lr;
                int rs = (r & 7) << 3;
#pragma unroll
                for (int kk = 0; kk < 4; ++kk) {
                    int c = kk * 32 + lq * 8;
                    bf16x8 bk = *reinterpret_cast<const bf16x8*>(&Ks[cur][r * 128 + (c ^ rs)]);
                    s0[jt] = MFMA16(bk, aq[0][kk], s0[jt]);
                    s1[jt] = MFMA16(bk, aq[1][kk], s1[jt]);
                }
            }
            __builtin_amdgcn_s_setprio(0);
            if (kt <= sA + 1 || kt == t1w) {
#pragma unroll
                for (int jt = 0; jt < 4; ++jt)
#pragma unroll
                    for (int j = 0; j < 4; ++j) {
                        int kj = j0 + jt * 16 + lq * 4 + j;
                        if (!(kj <= qi0 && kj > qi0 - 1024)) s0[jt][j] = -1e30f;
                    }
            }
            if (kt <= sB + 1 || kt == t1w) {
#pragma unroll
                for (int jt = 0; jt < 4; ++jt)
#pragma unroll
                    for (int j = 0; j < 4; ++j) {
                        int kj = j0 + jt * 16 + lq * 4 + j;
                        if (!(kj <= qi1 && kj > qi1 - 1024)) s1[jt][j] = -1e30f;
                    }
            }
            unsigned pk0[4][2], pk1[4][2];
#pragma unroll
            for (int jt = 0; jt < 4; ++jt)
#pragma unroll
                for (int hh = 0; hh < 2; ++hh) {
                    float p0 = exp2f(s0[jt][2 * hh] - 11.5415603f);
                    float p1 = exp2f(s0[jt][2 * hh + 1] - 11.5415603f);
                    lsum0 += p0 + p1;
                    asm("v_cvt_pk_bf16_f32 %0, %1, %2" : "=v"(pk0[jt][hh]) : "v"(p0), "v"(p1));
                }
#pragma unroll
            for (int jt = 0; jt < 4; ++jt)
#pragma unroll
                for (int hh = 0; hh < 2; ++hh) {
                    float p0 = exp2f(s1[jt][2 * hh] - 11.5415603f);
                    float p1 = exp2f(s1[jt][2 * hh + 1] - 11.5415603f);
                    lsum1 += p0 + p1;
                    asm("v_cvt_pk_bf16_f32 %0, %1, %2" : "=v"(pk1[jt][hh]) : "v"(p0), "v"(p1));
                }
            __builtin_amdgcn_s_setprio(1);
#pragma unroll
            for (int kk2 = 0; kk2 < 2; ++kk2) {
                union { unsigned u[4]; bf16x8 v; } pu0, pu1;
                pu0.u[0] = pk0[2 * kk2][0]; pu0.u[1] = pk0[2 * kk2][1];
                pu0.u[2] = pk0[2 * kk2 + 1][0]; pu0.u[3] = pk0[2 * kk2 + 1][1];
                pu1.u[0] = pk1[2 * kk2][0]; pu1.u[1] = pk1[2 * kk2][1];
                pu1.u[2] = pk1[2 * kk2 + 1][0]; pu1.u[3] = pk1[2 * kk2 + 1][1];
#pragma unroll
                for (int dt = 0; dt < 8; ++dt) {
                    int r = dt * 16 + lr;
                    int c = kk2 * 32 + lq * 8;
                    bf16x8 bv = *reinterpret_cast<const bf16x8*>(&Vs[cur][r * 64 + (c ^ ((r & 7) << 3))]);
                    o0[dt] = MFMA16(pu0.v, bv, o0[dt]);
                    o1[dt] = MFMA16(pu1.v, bv, o1[dt]);
                }
            }
            __builtin_amdgcn_s_setprio(0);
        }
        __builtin_amdgcn_s_barrier();
        cur ^= 1;
    }
    float lt0 = lsum0, lt1 = lsum1;
    lt0 += __shfl_xor(lt0, 16, 64);  lt0 += __shfl_xor(lt0, 32, 64);
    lt1 += __shfl_xor(lt1, 16, 64);  lt1 += __shfl_xor(lt1, 32, 64);
    float li0 = 1.0f / lt0, li1 = 1.0f / lt1;
    float lv0[4], lv1[4];
#pragma unroll
    for (int j = 0; j < 4; ++j) {
        lv0[j] = __shfl(li0, lq * 4 + j, 64);
        lv1[j] = __shfl(li1, lq * 4 + j, 64);
    }
#pragma unroll
    for (int dt = 0; dt < 8; ++dt)
#pragma unroll
        for (int j = 0; j < 4; ++j) {
            size_t base = (size_t)(b * 4096 + row0 + lq * 4 + j) * 2048 + h * 128 + dt * 16 + lr;
            ao[base] = __float2bfloat16(o0[dt][j] * lv0[j]);
            ao[base + (size_t)16 * 2048] = __float2bfloat16(o1[dt][j] * lv1[j]);
        }
}

extern "C" void kernel_launch(void* const* d_in, const int* in_sizes, int n_in,
                              void* d_out, int out_size, void* d_ws, size_t ws_size,
                              hipStream_t stream) {
    const float* x    = (const float*)d_in[0];
    const float* cosT = (const float*)d_in[1];
    const float* sinT = (const float*)d_in[2];
    const float* Wq   = (const float*)d_in[3];
    const float* Wk   = (const float*)d_in[4];
    const float* Wv   = (const float*)d_in[5];
    const float* Wo   = (const float*)d_in[6];
    const float* qnw  = (const float*)d_in[7];
    const float* knw  = (const float*)d_in[8];

    char* ws = (char*)d_ws;
    bf16* xb    = (bf16*)(ws);                 // 33,554,432 B  [8192][2048]
    bf16* wqkvT = (bf16*)(ws + 33554432);      // 12,582,912 B  [3072][2048]
    bf16* woT   = (bf16*)(ws + 46137344);      //  8,388,608 B  [2048][2048]
    bf16* qh    = (bf16*)(ws + 54525952);      // 33,554,432 B  [2][16][4096][128]
    bf16* kh    = (bf16*)(ws + 88080384);      //  8,388,608 B  [2][4][4096][128]
    bf16* vt    = (bf16*)(ws + 96468992);      //  8,388,608 B  [2][4][128][4096] -> total 100 MiB
    bf16* ao    = xb;                          // alias: xb dead after GEMM1
    bf16* qkv   = (bf16*)d_out;                // d_out as scratch: overwritten by GEMM2

    cvt_bf16_kernel<<<8192, 256, 0, stream>>>(x, xb, 16777216);
    transpose_wqkv_kernel<<<dim3(64, 96), 256, 0, stream>>>(Wq, Wk, Wv, wqkvT);
    transpose_w_kernel<<<dim3(64, 64), 256, 0, stream>>>(Wo, woT);
    // GEMM1: 128x192 tiles -> 64x16 = 1024 blocks = 2 exact rounds at 2 blocks/CU
    gemmocc_kernel<3, false><<<1024, 512, 0, stream>>>(xb, wqkvT, (void*)qkv, 8192, 3072, 2048, 16);
    normrope_kernel<<<40960, 256, 0, stream>>>(qkv, cosT, sinT, qnw, knw, qh, kh);
    vtrans_kernel<<<dim3(64, 8), 256, 0, stream>>>(qkv, vt);
    attn_kernel<<<512, 512, 0, stream>>>(qh, kh, vt, ao);
    // GEMM2: 128x128 tiles -> 64x16 = 1024 blocks = 2 exact rounds at 2 blocks/CU
    gemmocc_kernel<2, true><<<1024, 512, 0, stream>>>(ao, woT, d_out, 8192, 2048, 2048, 16);
}

// Round 15
// 338.171 us; speedup vs baseline: 1.4034x; 1.0113x over previous
//
#include <hip/hip_runtime.h>
#include <hip/hip_bf16.h>

typedef __hip_bfloat16 bf16;
typedef __attribute__((ext_vector_type(8))) __bf16 bf16x8;
typedef __attribute__((ext_vector_type(4))) float f32x4;

#define MFMA16(a, b, c) __builtin_amdgcn_mfma_f32_16x16x32_bf16((a), (b), (c), 0, 0, 0)

static __device__ __forceinline__ void gload_lds16(const void* g, void* l) {
    typedef const __attribute__((address_space(1))) unsigned gq_t;
    typedef __attribute__((address_space(3))) unsigned ls_t;
    __builtin_amdgcn_global_load_lds((gq_t*)g, (ls_t*)l, 16, 0, 0);
}

static __device__ __forceinline__ unsigned short f2bfbits(float f) {
    bf16 h = __float2bfloat16(f);
    return *reinterpret_cast<unsigned short*>(&h);
}

// ---------------- prepass: f32 -> bf16 cast of x ----------------
__global__ __launch_bounds__(256) void cvt_bf16_kernel(const float* __restrict__ in,
                                                       bf16* __restrict__ out, int n) {
    int i = (blockIdx.x * 256 + threadIdx.x) * 8;
    if (i < n) {
        float4 a = *reinterpret_cast<const float4*>(in + i);
        float4 b = *reinterpret_cast<const float4*>(in + i + 4);
        bf16 tmp[8];
        tmp[0] = __float2bfloat16(a.x); tmp[1] = __float2bfloat16(a.y);
        tmp[2] = __float2bfloat16(a.z); tmp[3] = __float2bfloat16(a.w);
        tmp[4] = __float2bfloat16(b.x); tmp[5] = __float2bfloat16(b.y);
        tmp[6] = __float2bfloat16(b.z); tmp[7] = __float2bfloat16(b.w);
        *reinterpret_cast<uint4*>(out + i) = *reinterpret_cast<const uint4*>(tmp);
    }
}

// ---------------- prepass: transpose Wq|Wk|Wv -> [3072][2048] bf16 ----------------
__global__ __launch_bounds__(256) void transpose_wqkv_kernel(const float* __restrict__ Wq,
                                                             const float* __restrict__ Wk,
                                                             const float* __restrict__ Wv,
                                                             bf16* __restrict__ out) {
    __shared__ float tile[32][33];
    int k0 = blockIdx.x * 32;   // along K (2048)
    int n0 = blockIdx.y * 32;   // along N (3072)
    int tx = threadIdx.x & 31, ty = threadIdx.x >> 5;  // 32 x 8
#pragma unroll
    for (int i = 0; i < 4; ++i) {
        int k = k0 + ty + i * 8, n = n0 + tx;
        float v;
        if (n < 2048)      v = Wq[(size_t)k * 2048 + n];
        else if (n < 2560) v = Wk[(size_t)k * 512 + (n - 2048)];
        else               v = Wv[(size_t)k * 512 + (n - 2560)];
        tile[ty + i * 8][tx] = v;
    }
    __syncthreads();
#pragma unroll
    for (int i = 0; i < 4; ++i)
        out[(size_t)(n0 + ty + i * 8) * 2048 + k0 + tx] = __float2bfloat16(tile[tx][ty + i * 8]);
}

// ---------------- prepass: transpose square W (2048x2048) -> bf16 ----------------
__global__ __launch_bounds__(256) void transpose_w_kernel(const float* __restrict__ in,
                                                          bf16* __restrict__ out) {
    __shared__ float tile[32][33];
    int k0 = blockIdx.x * 32, n0 = blockIdx.y * 32;
    int tx = threadIdx.x & 31, ty = threadIdx.x >> 5;
#pragma unroll
    for (int i = 0; i < 4; ++i)
        tile[ty + i * 8][tx] = in[(size_t)(k0 + ty + i * 8) * 2048 + n0 + tx];
    __syncthreads();
#pragma unroll
    for (int i = 0; i < 4; ++i)
        out[(size_t)(n0 + ty + i * 8) * 2048 + k0 + tx] = __float2bfloat16(tile[tx][ty + i * 8]);
}

// ---------------- occupancy-GEMM (R14-verified): 128 x (NFRAG*64) tile, 2 blocks/CU ----
template <int NFRAG, bool OUT_F32>
__global__ __launch_bounds__(512, 4) void gemmocc_kernel(const bf16* __restrict__ A,
                                                         const bf16* __restrict__ BT,
                                                         void* __restrict__ Cv,
                                                         int M, int N, int K, int nbn) {
    constexpr int BN = NFRAG * 64;
    constexpr int PB = NFRAG;          // B pieces per K-tile (1 gload/thread each)
    __shared__ bf16 As[2][128 * 64];   // 16 KiB per slot
    __shared__ bf16 Bs[2][BN * 64];
    int t = threadIdx.x;
    int lane = t & 63, w = t >> 6;
    int wm = w >> 2, wn = w & 3;       // 2 x 4 wave grid; per-wave C = 64 x NFRAG*16
    int lr = lane & 15, lq = lane >> 4;
    int lin = blockIdx.x;
    int cpx = gridDim.x >> 3;          // bijective XCD-chunked swizzle (grid % 8 == 0)
    int wg = (lin & 7) * cpx + (lin >> 3);
    int bm = wg / nbn, bn = wg % nbn;
    const bf16* Ab = A + (size_t)bm * 128 * K;
    const bf16* Bb = BT + (size_t)bn * BN * K;

    auto stA = [&](int slot, int kt, int piece) {
        int idx = piece * 512 + t;
        int r = idx >> 3, c8 = idx & 7;
        gload_lds16(Ab + (size_t)r * K + kt * 64 + ((c8 ^ (r & 7)) * 8), &As[slot][idx * 8]);
    };
    auto stB = [&](int slot, int kt, int piece) {
        int idx = piece * 512 + t;
        int r = idx >> 3, c8 = idx & 7;
        gload_lds16(Bb + (size_t)r * K + kt * 64 + ((c8 ^ (r & 7)) * 8), &Bs[slot][idx * 8]);
    };

    f32x4 acc[4][NFRAG] = {};
    bf16x8 bq[NFRAG][2], af[2][2];

    auto readB = [&](int slot) {
#pragma unroll
        for (int n = 0; n < NFRAG; ++n)
#pragma unroll
            for (int ks = 0; ks < 2; ++ks) {
                int ro = wn * (NFRAG * 16) + n * 16 + lr;
                int ch = (ks * 4 + lq) ^ (ro & 7);
                bq[n][ks] = *reinterpret_cast<const bf16x8*>(&Bs[slot][ro * 64 + ch * 8]);
            }
    };
    auto readA = [&](int mbase, int slot) {
#pragma unroll
        for (int mi = 0; mi < 2; ++mi)
#pragma unroll
            for (int ks = 0; ks < 2; ++ks) {
                int ro = wm * 64 + (mbase + mi) * 16 + lr;
                int ch = (ks * 4 + lq) ^ (ro & 7);
                af[mi][ks] = *reinterpret_cast<const bf16x8*>(&As[slot][ro * 64 + ch * 8]);
            }
    };
    auto mf = [&](int mbase) {
#pragma unroll
        for (int mi = 0; mi < 2; ++mi)
#pragma unroll
            for (int n = 0; n < NFRAG; ++n)
#pragma unroll
                for (int ks = 0; ks < 2; ++ks)
                    acc[mbase + mi][n] = MFMA16(af[mi][ks], bq[n][ks], acc[mbase + mi][n]);
    };

#define GATE_PB() asm volatile("s_waitcnt vmcnt(%0)" :: "i"(PB) : "memory")
#define PHASE_TAIL()                                                       \
    do {                                                                   \
        __builtin_amdgcn_s_barrier();                                      \
        asm volatile("s_waitcnt lgkmcnt(0)" ::: "memory");                 \
    } while (0)
#define MFMA_CLUSTER(mb)                                                   \
    do {                                                                   \
        __builtin_amdgcn_s_setprio(1);                                     \
        mf(mb);                                                            \
        __builtin_amdgcn_s_setprio(0);                                     \
        __builtin_amdgcn_s_barrier();                                      \
    } while (0)

    int nkt = K >> 6;   // even (K=2048 -> 32)
    stA(0, 0, 0); stA(0, 0, 1);
#pragma unroll
    for (int p = 0; p < PB; ++p) stB(0, 0, p);
#pragma unroll
    for (int p = 0; p < PB; ++p) stB(1, 1, p);
    GATE_PB();
    __builtin_amdgcn_s_barrier();

    int nI = nkt >> 1;
    for (int I = 0; I < nI; ++I) {
        int T = I << 1;
        bool s2 = (T + 2) < nkt;
        // ---- ph1: tile T (s0), m0-1; stage A(T+1) -> s1 ----
        readB(0); readA(0, 0);
        stA(1, T + 1, 0); stA(1, T + 1, 1);
        PHASE_TAIL();
        MFMA_CLUSTER(0);
        // ---- ph2: m2-3; stage B(T+2) -> s0; GATE certifies T+1 ----
        readA(2, 0);
        if (s2) {
#pragma unroll
            for (int p = 0; p < PB; ++p) stB(0, T + 2, p);
            GATE_PB();
        } else {
            asm volatile("s_waitcnt vmcnt(0)" ::: "memory");
        }
        PHASE_TAIL();
        MFMA_CLUSTER(2);
        // ---- ph3: tile T+1 (s1), m0-1; stage A(T+2) -> s0 ----
        readB(1); readA(0, 1);
        if (s2) { stA(0, T + 2, 0); stA(0, T + 2, 1); }
        PHASE_TAIL();
        MFMA_CLUSTER(0);
        // ---- ph4: m2-3; stage B(T+3) -> s1; GATE certifies T+2 ----
        readA(2, 1);
        if (s2) {
#pragma unroll
            for (int p = 0; p < PB; ++p) stB(1, T + 3, p);
            GATE_PB();
        } else {
            asm volatile("s_waitcnt vmcnt(0)" ::: "memory");
        }
        PHASE_TAIL();
        MFMA_CLUSTER(2);
    }
#undef GATE_PB
#undef PHASE_TAIL
#undef MFMA_CLUSTER

#pragma unroll
    for (int m = 0; m < 4; ++m)
#pragma unroll
        for (int n = 0; n < NFRAG; ++n) {
            int row = bm * 128 + wm * 64 + m * 16 + lq * 4;
            int col = bn * BN + wn * (NFRAG * 16) + n * 16 + lr;
#pragma unroll
            for (int j = 0; j < 4; ++j) {
                if (OUT_F32)
                    ((float*)Cv)[(size_t)(row + j) * N + col] = acc[m][n][j];
                else
                    ((bf16*)Cv)[(size_t)(row + j) * N + col] = __float2bfloat16(acc[m][n][j]);
            }
        }
}

// ---------------- fused RMSNorm+RoPE (Q,K) and V-transpose ----------------
// blocks [0, 40960): normrope on slot (blk%5)*4+wave; blocks [40960, 41472): vtrans.
__global__ __launch_bounds__(256) void normrope_vtrans_kernel(const bf16* __restrict__ qkv,
                                                              const float* __restrict__ cosT,
                                                              const float* __restrict__ sinT,
                                                              const float* __restrict__ qnw,
                                                              const float* __restrict__ knw,
                                                              bf16* __restrict__ qh,
                                                              bf16* __restrict__ kh,
                                                              bf16* __restrict__ vt) {
    __shared__ bf16 tile[64][132];   // used by vtrans blocks only
    int t = threadIdx.x;
    int blk = blockIdx.x;
    if (blk < 40960) {
        int lane = t & 63, wv = t >> 6;
        int r = blk / 5;
        int s = (blk % 5) * 4 + wv;     // slot 0..19: 0-15 Q heads, 16-19 K groups
        int b = r >> 12, l = r & 4095;
        int e0 = lane * 2;
        const bf16* src = qkv + (size_t)r * 3072 + s * 128;
        ushort2 xu = *reinterpret_cast<const ushort2*>(src + e0);
        float v0 = __uint_as_float((unsigned)xu.x << 16);
        float v1 = __uint_as_float((unsigned)xu.y << 16);
        float ss = v0 * v0 + v1 * v1;
#pragma unroll
        for (int d = 1; d < 64; d <<= 1) ss += __shfl_xor(ss, d, 64);
        float rn = rsqrtf(ss * (1.0f / 128.0f) + 1e-6f);
        const float* wn = (s < 16) ? qnw : knw;
        float2 wv2 = *reinterpret_cast<const float2*>(wn + e0);
        float xn0 = v0 * rn * wv2.x;
        float xn1 = v1 * rn * wv2.y;
        float xp0 = __shfl_xor(xn0, 32, 64);
        float xp1 = __shfl_xor(xn1, 32, 64);
        float r0 = (lane < 32) ? -xp0 : xp0;
        float r1 = (lane < 32) ? -xp1 : xp1;
        float2 c2 = *reinterpret_cast<const float2*>(cosT + (size_t)l * 128 + e0);
        float2 s2 = *reinterpret_cast<const float2*>(sinT + (size_t)l * 128 + e0);
        float o0 = xn0 * c2.x + r0 * s2.x;
        float o1 = xn1 * c2.y + r1 * s2.y;
        ushort2 ou;
        if (s < 16) {
            const float scl = 0.0625f * 1.44269504088896f;  // SCALE * log2(e) folded into q
            ou.x = f2bfbits(o0 * scl);
            ou.y = f2bfbits(o1 * scl);
            bf16* dst = qh + ((size_t)(b * 16 + s) * 4096 + l) * 128;
            *reinterpret_cast<ushort2*>(dst + e0) = ou;
        } else {
            int g = s - 16;
            ou.x = f2bfbits(o0);
            ou.y = f2bfbits(o1);
            int sw = (l & 7) << 3;   // bits >=3: pair adjacency + 4B alignment preserved
            bf16* dst = kh + ((size_t)(b * 4 + g) * 4096 + l) * 128;
            *reinterpret_cast<ushort2*>(dst + (e0 ^ sw)) = ou;
        }
    } else {
        int bid2 = blk - 40960;          // 0..511
        int l0 = (bid2 & 63) * 64;
        int bg = bid2 >> 6;              // b*4+g
        int b = bg >> 2, g = bg & 3;
        const bf16* src = qkv + ((size_t)(b * 4096 + l0)) * 3072 + 2560 + g * 128;
#pragma unroll
        for (int i = 0; i < 4; ++i) {
            int c = i * 256 + t;
            int r = c >> 4, c16 = c & 15;
            uint4 v = *reinterpret_cast<const uint4*>(src + (size_t)r * 3072 + c16 * 8);
            *reinterpret_cast<uint2*>(&tile[r][c16 * 8]) = make_uint2(v.x, v.y);
            *reinterpret_cast<uint2*>(&tile[r][c16 * 8 + 4]) = make_uint2(v.z, v.w);
        }
        __syncthreads();
        bf16* dst = vt + (size_t)bg * 128 * 4096 + l0;
        int cj = t & 63;
        int pos = (cj & 0x23) | ((cj & 16) >> 2) | ((cj & 12) << 1);  // sigma(cj)
#pragma unroll
        for (int dd = 0; dd < 32; ++dd) {
            int d = (t >> 6) * 32 + dd;
            dst[(size_t)d * 4096 + (pos ^ ((d & 7) << 3))] = tile[cj][d];
        }
    }
}

// ---------------- sliding-window flash attention (MFMA row-sum via ones operand) ----------------
__global__ __launch_bounds__(512, 2) void attn_kernel(const bf16* __restrict__ qh,
                                                      const bf16* __restrict__ kh,
                                                      const bf16* __restrict__ vt,
                                                      bf16* __restrict__ ao) {
    __shared__ bf16 Ks[2][64 * 128];    // 32 KiB
    __shared__ bf16 Vs[2][128 * 64];    // 32 KiB -> 64 KiB total
    int t = threadIdx.x;
    int lane = t & 63, w = t >> 6;
    int lr = lane & 15, lq = lane >> 4;
    int bid = blockIdx.x;
    int bh = (bid & 7) * 4 + (bid >> 7);     // XCD-resident K/V mapping (bijective, 512 blocks)
    int qs = ((bid >> 3) & 15) * 256;
    int b = bh >> 4, h = bh & 15, g = h >> 2;
    int row0 = qs + w * 32;
    const bf16* qp = qh + ((size_t)(b * 16 + h) * 4096 + row0) * 128;
    const bf16* kp = kh + (size_t)(b * 4 + g) * 4096 * 128;
    const bf16* vp = vt + (size_t)(b * 4 + g) * 128 * 4096;

    bf16x8 aq[2][4];
#pragma unroll
    for (int g2 = 0; g2 < 2; ++g2)
#pragma unroll
        for (int kk = 0; kk < 4; ++kk)
            aq[g2][kk] = *reinterpret_cast<const bf16x8*>(qp + (size_t)(g2 * 16 + lr) * 128 + kk * 32 + lq * 8);

    // all-ones bf16 fragment: row-sum collector B-operand (k-order invariant)
    union { unsigned short u[8]; bf16x8 v; } onesu;
#pragma unroll
    for (int k = 0; k < 8; ++k) onesu.u[k] = 0x3F80;
    bf16x8 ones = onesu.v;

    f32x4 o0[8] = {}, o1[8] = {};
    f32x4 osum0 = {}, osum1 = {};            // D-row = q (lq*4+j), replicated over lr
    int qi0 = row0 + lr, qi1 = row0 + 16 + lr;
    int sA = max(0, row0 - 1023) >> 6;
    int sB = max(0, row0 + 16 - 1023) >> 6;
    int t1w = row0 >> 6;
    int t0w = sA;
    int t0 = max(0, qs - 1023) >> 6;
    int t1 = (qs + 255) >> 6;

    auto stage = [&](int buf, int kt) {
        int j0 = kt * 64;
        const bf16* kg = kp + (size_t)j0 * 128;
#pragma unroll
        for (int i = 0; i < 2; ++i) {
            int c = i * 512 + t;
            gload_lds16(kg + c * 8, &Ks[buf][c * 8]);
        }
#pragma unroll
        for (int i = 0; i < 2; ++i) {
            int c = i * 512 + t;
            int d = c >> 3, co = (c & 7) * 8;
            gload_lds16(vp + (size_t)d * 4096 + j0 + co, &Vs[buf][c * 8]);
        }
    };

    stage(0, t0);
    int cur = 0;

    for (int kt = t0; kt <= t1; ++kt) {
        if (kt < t1) {
            stage(cur ^ 1, kt + 1);
            asm volatile("s_waitcnt vmcnt(4)" ::: "memory");
        } else {
            asm volatile("s_waitcnt vmcnt(0)" ::: "memory");
        }
        __builtin_amdgcn_s_barrier();
        if (kt >= t0w && kt <= t1w) {
            int j0 = kt * 64;
            f32x4 s0[4] = {}, s1[4] = {};
            __builtin_amdgcn_s_setprio(1);
#pragma unroll
            for (int jt = 0; jt < 4; ++jt) {
                int r = jt * 16 + lr;
                int rs = (r & 7) << 3;
#pragma unroll
                for (int kk = 0; kk < 4; ++kk) {
                    int c = kk * 32 + lq * 8;
                    bf16x8 bk = *reinterpret_cast<const bf16x8*>(&Ks[cur][r * 128 + (c ^ rs)]);
                    s0[jt] = MFMA16(bk, aq[0][kk], s0[jt]);
                    s1[jt] = MFMA16(bk, aq[1][kk], s1[jt]);
                }
            }
            __builtin_amdgcn_s_setprio(0);
            if (kt <= sA + 1 || kt == t1w) {
#pragma unroll
                for (int jt = 0; jt < 4; ++jt)
#pragma unroll
                    for (int j = 0; j < 4; ++j) {
                        int kj = j0 + jt * 16 + lq * 4 + j;
                        if (!(kj <= qi0 && kj > qi0 - 1024)) s0[jt][j] = -1e30f;
                    }
            }
            if (kt <= sB + 1 || kt == t1w) {
#pragma unroll
                for (int jt = 0; jt < 4; ++jt)
#pragma unroll
                    for (int j = 0; j < 4; ++j) {
                        int kj = j0 + jt * 16 + lq * 4 + j;
                        if (!(kj <= qi1 && kj > qi1 - 1024)) s1[jt][j] = -1e30f;
                    }
            }
            // ---- fixed-shift softmax + in-register bf16 pack (no scalar row-sum) ----
            unsigned pk0[4][2], pk1[4][2];
#pragma unroll
            for (int jt = 0; jt < 4; ++jt)
#pragma unroll
                for (int hh = 0; hh < 2; ++hh) {
                    float p0 = exp2f(s0[jt][2 * hh] - 11.5415603f);
                    float p1 = exp2f(s0[jt][2 * hh + 1] - 11.5415603f);
                    asm("v_cvt_pk_bf16_f32 %0, %1, %2" : "=v"(pk0[jt][hh]) : "v"(p0), "v"(p1));
                }
#pragma unroll
            for (int jt = 0; jt < 4; ++jt)
#pragma unroll
                for (int hh = 0; hh < 2; ++hh) {
                    float p0 = exp2f(s1[jt][2 * hh] - 11.5415603f);
                    float p1 = exp2f(s1[jt][2 * hh + 1] - 11.5415603f);
                    asm("v_cvt_pk_bf16_f32 %0, %1, %2" : "=v"(pk1[jt][hh]) : "v"(p0), "v"(p1));
                }
            // ---- O += P V; row-sums ride the matrix pipe (B = ones) ----
            __builtin_amdgcn_s_setprio(1);
#pragma unroll
            for (int kk2 = 0; kk2 < 2; ++kk2) {
                union { unsigned u[4]; bf16x8 v; } pu0, pu1;
                pu0.u[0] = pk0[2 * kk2][0]; pu0.u[1] = pk0[2 * kk2][1];
                pu0.u[2] = pk0[2 * kk2 + 1][0]; pu0.u[3] = pk0[2 * kk2 + 1][1];
                pu1.u[0] = pk1[2 * kk2][0]; pu1.u[1] = pk1[2 * kk2][1];
                pu1.u[2] = pk1[2 * kk2 + 1][0]; pu1.u[3] = pk1[2 * kk2 + 1][1];
                osum0 = MFMA16(pu0.v, ones, osum0);
                osum1 = MFMA16(pu1.v, ones, osum1);
#pragma unroll
                for (int dt = 0; dt < 8; ++dt) {
                    int r = dt * 16 + lr;
                    int c = kk2 * 32 + lq * 8;
                    bf16x8 bv = *reinterpret_cast<const bf16x8*>(&Vs[cur][r * 64 + (c ^ ((r & 7) << 3))]);
                    o0[dt] = MFMA16(pu0.v, bv, o0[dt]);
                    o1[dt] = MFMA16(pu1.v, bv, o1[dt]);
                }
            }
            __builtin_amdgcn_s_setprio(0);
        }
        __builtin_amdgcn_s_barrier();
        cur ^= 1;
    }
    // ---- epilogue: linv already on the right lanes (D-row = q), no shuffles ----
    float lv0[4], lv1[4];
#pragma unroll
    for (int j = 0; j < 4; ++j) {
        lv0[j] = 1.0f / osum0[j];
        lv1[j] = 1.0f / osum1[j];
    }
#pragma unroll
    for (int dt = 0; dt < 8; ++dt)
#pragma unroll
        for (int j = 0; j < 4; ++j) {
            size_t base = (size_t)(b * 4096 + row0 + lq * 4 + j) * 2048 + h * 128 + dt * 16 + lr;
            ao[base] = __float2bfloat16(o0[dt][j] * lv0[j]);
            ao[base + (size_t)16 * 2048] = __float2bfloat16(o1[dt][j] * lv1[j]);
        }
}

extern "C" void kernel_launch(void* const* d_in, const int* in_sizes, int n_in,
                              void* d_out, int out_size, void* d_ws, size_t ws_size,
                              hipStream_t stream) {
    const float* x    = (const float*)d_in[0];
    const float* cosT = (const float*)d_in[1];
    const float* sinT = (const float*)d_in[2];
    const float* Wq   = (const float*)d_in[3];
    const float* Wk   = (const float*)d_in[4];
    const float* Wv   = (const float*)d_in[5];
    const float* Wo   = (const float*)d_in[6];
    const float* qnw  = (const float*)d_in[7];
    const float* knw  = (const float*)d_in[8];

    char* ws = (char*)d_ws;
    bf16* xb    = (bf16*)(ws);                 // 33,554,432 B  [8192][2048]
    bf16* wqkvT = (bf16*)(ws + 33554432);      // 12,582,912 B  [3072][2048]
    bf16* woT   = (bf16*)(ws + 46137344);      //  8,388,608 B  [2048][2048]
    bf16* qh    = (bf16*)(ws + 54525952);      // 33,554,432 B  [2][16][4096][128]
    bf16* kh    = (bf16*)(ws + 88080384);      //  8,388,608 B  [2][4][4096][128]
    bf16* vt    = (bf16*)(ws + 96468992);      //  8,388,608 B  [2][4][128][4096] -> total 100 MiB
    bf16* ao    = xb;                          // alias: xb dead after GEMM1
    bf16* qkv   = (bf16*)d_out;                // d_out as scratch: overwritten by GEMM2

    cvt_bf16_kernel<<<8192, 256, 0, stream>>>(x, xb, 16777216);
    transpose_wqkv_kernel<<<dim3(64, 96), 256, 0, stream>>>(Wq, Wk, Wv, wqkvT);
    transpose_w_kernel<<<dim3(64, 64), 256, 0, stream>>>(Wo, woT);
    // GEMM1: 128x192 tiles -> 1024 blocks = 2 exact rounds at 2 blocks/CU (R14 best)
    gemmocc_kernel<3, false><<<1024, 512, 0, stream>>>(xb, wqkvT, (void*)qkv, 8192, 3072, 2048, 16);
    normrope_vtrans_kernel<<<41472, 256, 0, stream>>>(qkv, cosT, sinT, qnw, knw, qh, kh, vt);
    attn_kernel<<<512, 512, 0, stream>>>(qh, kh, vt, ao);
    // GEMM2: 128x128 tiles -> 1024 blocks = 2 exact rounds at 2 blocks/CU (R14 best)
    gemmocc_kernel<2, true><<<1024, 512, 0, stream>>>(ao, woT, d_out, 8192, 2048, 2048, 16);
}

// Round 16
// 337.833 us; speedup vs baseline: 1.4048x; 1.0010x over previous
//
#include <hip/hip_runtime.h>
#include <hip/hip_bf16.h>

typedef __hip_bfloat16 bf16;
typedef __attribute__((ext_vector_type(8))) __bf16 bf16x8;
typedef __attribute__((ext_vector_type(4))) float f32x4;

#define MFMA16(a, b, c) __builtin_amdgcn_mfma_f32_16x16x32_bf16((a), (b), (c), 0, 0, 0)

static __device__ __forceinline__ void gload_lds16(const void* g, void* l) {
    typedef const __attribute__((address_space(1))) unsigned gq_t;
    typedef __attribute__((address_space(3))) unsigned ls_t;
    __builtin_amdgcn_global_load_lds((gq_t*)g, (ls_t*)l, 16, 0, 0);
}

static __device__ __forceinline__ unsigned short f2bfbits(float f) {
    bf16 h = __float2bfloat16(f);
    return *reinterpret_cast<unsigned short*>(&h);
}

// ---------------- prepass: f32 -> bf16 cast of x ----------------
__global__ __launch_bounds__(256) void cvt_bf16_kernel(const float* __restrict__ in,
                                                       bf16* __restrict__ out, int n) {
    int i = (blockIdx.x * 256 + threadIdx.x) * 8;
    if (i < n) {
        float4 a = *reinterpret_cast<const float4*>(in + i);
        float4 b = *reinterpret_cast<const float4*>(in + i + 4);
        bf16 tmp[8];
        tmp[0] = __float2bfloat16(a.x); tmp[1] = __float2bfloat16(a.y);
        tmp[2] = __float2bfloat16(a.z); tmp[3] = __float2bfloat16(a.w);
        tmp[4] = __float2bfloat16(b.x); tmp[5] = __float2bfloat16(b.y);
        tmp[6] = __float2bfloat16(b.z); tmp[7] = __float2bfloat16(b.w);
        *reinterpret_cast<uint4*>(out + i) = *reinterpret_cast<const uint4*>(tmp);
    }
}

// ---------------- prepass: transpose Wq|Wk|Wv -> [3072][2048] bf16 ----------------
__global__ __launch_bounds__(256) void transpose_wqkv_kernel(const float* __restrict__ Wq,
                                                             const float* __restrict__ Wk,
                                                             const float* __restrict__ Wv,
                                                             bf16* __restrict__ out) {
    __shared__ float tile[32][33];
    int k0 = blockIdx.x * 32;   // along K (2048)
    int n0 = blockIdx.y * 32;   // along N (3072)
    int tx = threadIdx.x & 31, ty = threadIdx.x >> 5;  // 32 x 8
#pragma unroll
    for (int i = 0; i < 4; ++i) {
        int k = k0 + ty + i * 8, n = n0 + tx;
        float v;
        if (n < 2048)      v = Wq[(size_t)k * 2048 + n];
        else if (n < 2560) v = Wk[(size_t)k * 512 + (n - 2048)];
        else               v = Wv[(size_t)k * 512 + (n - 2560)];
        tile[ty + i * 8][tx] = v;
    }
    __syncthreads();
#pragma unroll
    for (int i = 0; i < 4; ++i)
        out[(size_t)(n0 + ty + i * 8) * 2048 + k0 + tx] = __float2bfloat16(tile[tx][ty + i * 8]);
}

// ---------------- prepass: transpose square W (2048x2048) -> bf16 ----------------
__global__ __launch_bounds__(256) void transpose_w_kernel(const float* __restrict__ in,
                                                          bf16* __restrict__ out) {
    __shared__ float tile[32][33];
    int k0 = blockIdx.x * 32, n0 = blockIdx.y * 32;
    int tx = threadIdx.x & 31, ty = threadIdx.x >> 5;
#pragma unroll
    for (int i = 0; i < 4; ++i)
        tile[ty + i * 8][tx] = in[(size_t)(k0 + ty + i * 8) * 2048 + n0 + tx];
    __syncthreads();
#pragma unroll
    for (int i = 0; i < 4; ++i)
        out[(size_t)(n0 + ty + i * 8) * 2048 + k0 + tx] = __float2bfloat16(tile[tx][ty + i * 8]);
}

// ---------------- occupancy-GEMM (R14-verified): 128 x (NFRAG*64) tile, 2 blocks/CU ----
template <int NFRAG, bool OUT_F32>
__global__ __launch_bounds__(512, 4) void gemmocc_kernel(const bf16* __restrict__ A,
                                                         const bf16* __restrict__ BT,
                                                         void* __restrict__ Cv,
                                                         int M, int N, int K, int nbn) {
    constexpr int BN = NFRAG * 64;
    constexpr int PB = NFRAG;          // B pieces per K-tile (1 gload/thread each)
    __shared__ bf16 As[2][128 * 64];   // 16 KiB per slot
    __shared__ bf16 Bs[2][BN * 64];
    int t = threadIdx.x;
    int lane = t & 63, w = t >> 6;
    int wm = w >> 2, wn = w & 3;       // 2 x 4 wave grid; per-wave C = 64 x NFRAG*16
    int lr = lane & 15, lq = lane >> 4;
    int lin = blockIdx.x;
    int cpx = gridDim.x >> 3;          // bijective XCD-chunked swizzle (grid % 8 == 0)
    int wg = (lin & 7) * cpx + (lin >> 3);
    int bm = wg / nbn, bn = wg % nbn;
    const bf16* Ab = A + (size_t)bm * 128 * K;
    const bf16* Bb = BT + (size_t)bn * BN * K;

    auto stA = [&](int slot, int kt, int piece) {
        int idx = piece * 512 + t;
        int r = idx >> 3, c8 = idx & 7;
        gload_lds16(Ab + (size_t)r * K + kt * 64 + ((c8 ^ (r & 7)) * 8), &As[slot][idx * 8]);
    };
    auto stB = [&](int slot, int kt, int piece) {
        int idx = piece * 512 + t;
        int r = idx >> 3, c8 = idx & 7;
        gload_lds16(Bb + (size_t)r * K + kt * 64 + ((c8 ^ (r & 7)) * 8), &Bs[slot][idx * 8]);
    };

    f32x4 acc[4][NFRAG] = {};
    bf16x8 bq[NFRAG][2], af[2][2];

    auto readB = [&](int slot) {
#pragma unroll
        for (int n = 0; n < NFRAG; ++n)
#pragma unroll
            for (int ks = 0; ks < 2; ++ks) {
                int ro = wn * (NFRAG * 16) + n * 16 + lr;
                int ch = (ks * 4 + lq) ^ (ro & 7);
                bq[n][ks] = *reinterpret_cast<const bf16x8*>(&Bs[slot][ro * 64 + ch * 8]);
            }
    };
    auto readA = [&](int mbase, int slot) {
#pragma unroll
        for (int mi = 0; mi < 2; ++mi)
#pragma unroll
            for (int ks = 0; ks < 2; ++ks) {
                int ro = wm * 64 + (mbase + mi) * 16 + lr;
                int ch = (ks * 4 + lq) ^ (ro & 7);
                af[mi][ks] = *reinterpret_cast<const bf16x8*>(&As[slot][ro * 64 + ch * 8]);
            }
    };
    auto mf = [&](int mbase) {
#pragma unroll
        for (int mi = 0; mi < 2; ++mi)
#pragma unroll
            for (int n = 0; n < NFRAG; ++n)
#pragma unroll
                for (int ks = 0; ks < 2; ++ks)
                    acc[mbase + mi][n] = MFMA16(af[mi][ks], bq[n][ks], acc[mbase + mi][n]);
    };

#define GATE_PB() asm volatile("s_waitcnt vmcnt(%0)" :: "i"(PB) : "memory")
#define PHASE_TAIL()                                                       \
    do {                                                                   \
        __builtin_amdgcn_s_barrier();                                      \
        asm volatile("s_waitcnt lgkmcnt(0)" ::: "memory");                 \
    } while (0)
#define MFMA_CLUSTER(mb)                                                   \
    do {                                                                   \
        __builtin_amdgcn_s_setprio(1);                                     \
        mf(mb);                                                            \
        __builtin_amdgcn_s_setprio(0);                                     \
        __builtin_amdgcn_s_barrier();                                      \
    } while (0)

    int nkt = K >> 6;   // even (K=2048 -> 32)
    stA(0, 0, 0); stA(0, 0, 1);
#pragma unroll
    for (int p = 0; p < PB; ++p) stB(0, 0, p);
#pragma unroll
    for (int p = 0; p < PB; ++p) stB(1, 1, p);
    GATE_PB();
    __builtin_amdgcn_s_barrier();

    int nI = nkt >> 1;
    for (int I = 0; I < nI; ++I) {
        int T = I << 1;
        bool s2 = (T + 2) < nkt;
        // ---- ph1: tile T (s0), m0-1; stage A(T+1) -> s1 ----
        readB(0); readA(0, 0);
        stA(1, T + 1, 0); stA(1, T + 1, 1);
        PHASE_TAIL();
        MFMA_CLUSTER(0);
        // ---- ph2: m2-3; stage B(T+2) -> s0; GATE certifies T+1 ----
        readA(2, 0);
        if (s2) {
#pragma unroll
            for (int p = 0; p < PB; ++p) stB(0, T + 2, p);
            GATE_PB();
        } else {
            asm volatile("s_waitcnt vmcnt(0)" ::: "memory");
        }
        PHASE_TAIL();
        MFMA_CLUSTER(2);
        // ---- ph3: tile T+1 (s1), m0-1; stage A(T+2) -> s0 ----
        readB(1); readA(0, 1);
        if (s2) { stA(0, T + 2, 0); stA(0, T + 2, 1); }
        PHASE_TAIL();
        MFMA_CLUSTER(0);
        // ---- ph4: m2-3; stage B(T+3) -> s1; GATE certifies T+2 ----
        readA(2, 1);
        if (s2) {
#pragma unroll
            for (int p = 0; p < PB; ++p) stB(1, T + 3, p);
            GATE_PB();
        } else {
            asm volatile("s_waitcnt vmcnt(0)" ::: "memory");
        }
        PHASE_TAIL();
        MFMA_CLUSTER(2);
    }
#undef GATE_PB
#undef PHASE_TAIL
#undef MFMA_CLUSTER

#pragma unroll
    for (int m = 0; m < 4; ++m)
#pragma unroll
        for (int n = 0; n < NFRAG; ++n) {
            int row = bm * 128 + wm * 64 + m * 16 + lq * 4;
            int col = bn * BN + wn * (NFRAG * 16) + n * 16 + lr;
#pragma unroll
            for (int j = 0; j < 4; ++j) {
                if (OUT_F32)
                    ((float*)Cv)[(size_t)(row + j) * N + col] = acc[m][n][j];
                else
                    ((bf16*)Cv)[(size_t)(row + j) * N + col] = __float2bfloat16(acc[m][n][j]);
            }
        }
}

// ---------------- fused RMSNorm+RoPE (Q,K) and V-transpose ----------------
__global__ __launch_bounds__(256) void normrope_vtrans_kernel(const bf16* __restrict__ qkv,
                                                              const float* __restrict__ cosT,
                                                              const float* __restrict__ sinT,
                                                              const float* __restrict__ qnw,
                                                              const float* __restrict__ knw,
                                                              bf16* __restrict__ qh,
                                                              bf16* __restrict__ kh,
                                                              bf16* __restrict__ vt) {
    __shared__ bf16 tile[64][132];   // used by vtrans blocks only
    int t = threadIdx.x;
    int blk = blockIdx.x;
    if (blk < 40960) {
        int lane = t & 63, wv = t >> 6;
        int r = blk / 5;
        int s = (blk % 5) * 4 + wv;     // slot 0..19: 0-15 Q heads, 16-19 K groups
        int b = r >> 12, l = r & 4095;
        int e0 = lane * 2;
        const bf16* src = qkv + (size_t)r * 3072 + s * 128;
        ushort2 xu = *reinterpret_cast<const ushort2*>(src + e0);
        float v0 = __uint_as_float((unsigned)xu.x << 16);
        float v1 = __uint_as_float((unsigned)xu.y << 16);
        float ss = v0 * v0 + v1 * v1;
#pragma unroll
        for (int d = 1; d < 64; d <<= 1) ss += __shfl_xor(ss, d, 64);
        float rn = rsqrtf(ss * (1.0f / 128.0f) + 1e-6f);
        const float* wn = (s < 16) ? qnw : knw;
        float2 wv2 = *reinterpret_cast<const float2*>(wn + e0);
        float xn0 = v0 * rn * wv2.x;
        float xn1 = v1 * rn * wv2.y;
        float xp0 = __shfl_xor(xn0, 32, 64);
        float xp1 = __shfl_xor(xn1, 32, 64);
        float r0 = (lane < 32) ? -xp0 : xp0;
        float r1 = (lane < 32) ? -xp1 : xp1;
        float2 c2 = *reinterpret_cast<const float2*>(cosT + (size_t)l * 128 + e0);
        float2 s2 = *reinterpret_cast<const float2*>(sinT + (size_t)l * 128 + e0);
        float o0 = xn0 * c2.x + r0 * s2.x;
        float o1 = xn1 * c2.y + r1 * s2.y;
        ushort2 ou;
        if (s < 16) {
            const float scl = 0.0625f * 1.44269504088896f;  // SCALE * log2(e) folded into q
            ou.x = f2bfbits(o0 * scl);
            ou.y = f2bfbits(o1 * scl);
            bf16* dst = qh + ((size_t)(b * 16 + s) * 4096 + l) * 128;
            *reinterpret_cast<ushort2*>(dst + e0) = ou;
        } else {
            int g = s - 16;
            ou.x = f2bfbits(o0);
            ou.y = f2bfbits(o1);
            int sw = (l & 7) << 3;   // bits >=3: pair adjacency + 4B alignment preserved
            bf16* dst = kh + ((size_t)(b * 4 + g) * 4096 + l) * 128;
            *reinterpret_cast<ushort2*>(dst + (e0 ^ sw)) = ou;
        }
    } else {
        int bid2 = blk - 40960;          // 0..511
        int l0 = (bid2 & 63) * 64;
        int bg = bid2 >> 6;              // b*4+g
        int b = bg >> 2, g = bg & 3;
        const bf16* src = qkv + ((size_t)(b * 4096 + l0)) * 3072 + 2560 + g * 128;
#pragma unroll
        for (int i = 0; i < 4; ++i) {
            int c = i * 256 + t;
            int r = c >> 4, c16 = c & 15;
            uint4 v = *reinterpret_cast<const uint4*>(src + (size_t)r * 3072 + c16 * 8);
            *reinterpret_cast<uint2*>(&tile[r][c16 * 8]) = make_uint2(v.x, v.y);
            *reinterpret_cast<uint2*>(&tile[r][c16 * 8 + 4]) = make_uint2(v.z, v.w);
        }
        __syncthreads();
        bf16* dst = vt + (size_t)bg * 128 * 4096 + l0;
        int cj = t & 63;
        int pos = (cj & 0x23) | ((cj & 16) >> 2) | ((cj & 12) << 1);  // sigma(cj)
#pragma unroll
        for (int dd = 0; dd < 32; ++dd) {
            int d = (t >> 6) * 32 + dd;
            dst[(size_t)d * 4096 + (pos ^ ((d & 7) << 3))] = tile[cj][d];
        }
    }
}

// ---------------- sliding-window flash attention: single-barrier 2-phase loop ----------------
// Canonical T3 minimal pattern: { vmcnt(0); barrier; stage(kt+1); compute(kt) }.
// One block barrier per KV-tile (was two). Stage issued AFTER the barrier so the same
// barrier orders (a) tile-kt data visibility and (b) WAR on slot^1 (last read at kt-1).
// Stage latency hides under compute(kt); vmcnt(0) at top is then nearly free.
__global__ __launch_bounds__(512, 2) void attn_kernel(const bf16* __restrict__ qh,
                                                      const bf16* __restrict__ kh,
                                                      const bf16* __restrict__ vt,
                                                      bf16* __restrict__ ao) {
    __shared__ bf16 Ks[2][64 * 128];    // 32 KiB
    __shared__ bf16 Vs[2][128 * 64];    // 32 KiB -> 64 KiB total
    int t = threadIdx.x;
    int lane = t & 63, w = t >> 6;
    int lr = lane & 15, lq = lane >> 4;
    int bid = blockIdx.x;
    int bh = (bid & 7) * 4 + (bid >> 7);     // XCD-resident K/V mapping (bijective, 512 blocks)
    int qs = ((bid >> 3) & 15) * 256;
    int b = bh >> 4, h = bh & 15, g = h >> 2;
    int row0 = qs + w * 32;
    const bf16* qp = qh + ((size_t)(b * 16 + h) * 4096 + row0) * 128;
    const bf16* kp = kh + (size_t)(b * 4 + g) * 4096 * 128;
    const bf16* vp = vt + (size_t)(b * 4 + g) * 128 * 4096;

    bf16x8 aq[2][4];
#pragma unroll
    for (int g2 = 0; g2 < 2; ++g2)
#pragma unroll
        for (int kk = 0; kk < 4; ++kk)
            aq[g2][kk] = *reinterpret_cast<const bf16x8*>(qp + (size_t)(g2 * 16 + lr) * 128 + kk * 32 + lq * 8);

    // all-ones bf16 fragment: row-sum collector B-operand (k-order invariant)
    union { unsigned short u[8]; bf16x8 v; } onesu;
#pragma unroll
    for (int k = 0; k < 8; ++k) onesu.u[k] = 0x3F80;
    bf16x8 ones = onesu.v;

    f32x4 o0[8] = {}, o1[8] = {};
    f32x4 osum0 = {}, osum1 = {};            // D-row = q (lq*4+j), replicated over lr
    int qi0 = row0 + lr, qi1 = row0 + 16 + lr;
    int sA = max(0, row0 - 1023) >> 6;
    int sB = max(0, row0 + 16 - 1023) >> 6;
    int t1w = row0 >> 6;
    int t0w = sA;
    int t0 = max(0, qs - 1023) >> 6;
    int t1 = (qs + 255) >> 6;

    auto stage = [&](int buf, int kt) {
        int j0 = kt * 64;
        const bf16* kg = kp + (size_t)j0 * 128;
#pragma unroll
        for (int i = 0; i < 2; ++i) {
            int c = i * 512 + t;
            gload_lds16(kg + c * 8, &Ks[buf][c * 8]);
        }
#pragma unroll
        for (int i = 0; i < 2; ++i) {
            int c = i * 512 + t;
            int d = c >> 3, co = (c & 7) * 8;
            gload_lds16(vp + (size_t)d * 4096 + j0 + co, &Vs[buf][c * 8]);
        }
    };

    stage(0, t0);                            // prologue stage of tile t0
    int cur = 0;

    for (int kt = t0; kt <= t1; ++kt) {
        asm volatile("s_waitcnt vmcnt(0)" ::: "memory");   // drain own stage(kt) loads
        __builtin_amdgcn_s_barrier();        // tile kt resident everywhere; compute(kt-1) done everywhere
        if (kt < t1) stage(cur ^ 1, kt + 1); // safe WAR: slot^1's readers finished before barrier
        if (kt >= t0w && kt <= t1w) {        // wave-uniform activity window
            int j0 = kt * 64;
            f32x4 s0[4] = {}, s1[4] = {};
            __builtin_amdgcn_s_setprio(1);
#pragma unroll
            for (int jt = 0; jt < 4; ++jt) {
                int r = jt * 16 + lr;
                int rs = (r & 7) << 3;
#pragma unroll
                for (int kk = 0; kk < 4; ++kk) {
                    int c = kk * 32 + lq * 8;
                    bf16x8 bk = *reinterpret_cast<const bf16x8*>(&Ks[cur][r * 128 + (c ^ rs)]);
                    s0[jt] = MFMA16(bk, aq[0][kk], s0[jt]);
                    s1[jt] = MFMA16(bk, aq[1][kk], s1[jt]);
                }
            }
            __builtin_amdgcn_s_setprio(0);
            if (kt <= sA + 1 || kt == t1w) {
#pragma unroll
                for (int jt = 0; jt < 4; ++jt)
#pragma unroll
                    for (int j = 0; j < 4; ++j) {
                        int kj = j0 + jt * 16 + lq * 4 + j;
                        if (!(kj <= qi0 && kj > qi0 - 1024)) s0[jt][j] = -1e30f;
                    }
            }
            if (kt <= sB + 1 || kt == t1w) {
#pragma unroll
                for (int jt = 0; jt < 4; ++jt)
#pragma unroll
                    for (int j = 0; j < 4; ++j) {
                        int kj = j0 + jt * 16 + lq * 4 + j;
                        if (!(kj <= qi1 && kj > qi1 - 1024)) s1[jt][j] = -1e30f;
                    }
            }
            unsigned pk0[4][2], pk1[4][2];
#pragma unroll
            for (int jt = 0; jt < 4; ++jt)
#pragma unroll
                for (int hh = 0; hh < 2; ++hh) {
                    float p0 = exp2f(s0[jt][2 * hh] - 11.5415603f);
                    float p1 = exp2f(s0[jt][2 * hh + 1] - 11.5415603f);
                    asm("v_cvt_pk_bf16_f32 %0, %1, %2" : "=v"(pk0[jt][hh]) : "v"(p0), "v"(p1));
                }
#pragma unroll
            for (int jt = 0; jt < 4; ++jt)
#pragma unroll
                for (int hh = 0; hh < 2; ++hh) {
                    float p0 = exp2f(s1[jt][2 * hh] - 11.5415603f);
                    float p1 = exp2f(s1[jt][2 * hh + 1] - 11.5415603f);
                    asm("v_cvt_pk_bf16_f32 %0, %1, %2" : "=v"(pk1[jt][hh]) : "v"(p0), "v"(p1));
                }
            __builtin_amdgcn_s_setprio(1);
#pragma unroll
            for (int kk2 = 0; kk2 < 2; ++kk2) {
                union { unsigned u[4]; bf16x8 v; } pu0, pu1;
                pu0.u[0] = pk0[2 * kk2][0]; pu0.u[1] = pk0[2 * kk2][1];
                pu0.u[2] = pk0[2 * kk2 + 1][0]; pu0.u[3] = pk0[2 * kk2 + 1][1];
                pu1.u[0] = pk1[2 * kk2][0]; pu1.u[1] = pk1[2 * kk2][1];
                pu1.u[2] = pk1[2 * kk2 + 1][0]; pu1.u[3] = pk1[2 * kk2 + 1][1];
                osum0 = MFMA16(pu0.v, ones, osum0);
                osum1 = MFMA16(pu1.v, ones, osum1);
#pragma unroll
                for (int dt = 0; dt < 8; ++dt) {
                    int r = dt * 16 + lr;
                    int c = kk2 * 32 + lq * 8;
                    bf16x8 bv = *reinterpret_cast<const bf16x8*>(&Vs[cur][r * 64 + (c ^ ((r & 7) << 3))]);
                    o0[dt] = MFMA16(pu0.v, bv, o0[dt]);
                    o1[dt] = MFMA16(pu1.v, bv, o1[dt]);
                }
            }
            __builtin_amdgcn_s_setprio(0);
        }
        cur ^= 1;
    }
    // ---- epilogue: linv already on the right lanes (D-row = q), no shuffles ----
    float lv0[4], lv1[4];
#pragma unroll
    for (int j = 0; j < 4; ++j) {
        lv0[j] = 1.0f / osum0[j];
        lv1[j] = 1.0f / osum1[j];
    }
#pragma unroll
    for (int dt = 0; dt < 8; ++dt)
#pragma unroll
        for (int j = 0; j < 4; ++j) {
            size_t base = (size_t)(b * 4096 + row0 + lq * 4 + j) * 2048 + h * 128 + dt * 16 + lr;
            ao[base] = __float2bfloat16(o0[dt][j] * lv0[j]);
            ao[base + (size_t)16 * 2048] = __float2bfloat16(o1[dt][j] * lv1[j]);
        }
}

extern "C" void kernel_launch(void* const* d_in, const int* in_sizes, int n_in,
                              void* d_out, int out_size, void* d_ws, size_t ws_size,
                              hipStream_t stream) {
    const float* x    = (const float*)d_in[0];
    const float* cosT = (const float*)d_in[1];
    const float* sinT = (const float*)d_in[2];
    const float* Wq   = (const float*)d_in[3];
    const float* Wk   = (const float*)d_in[4];
    const float* Wv   = (const float*)d_in[5];
    const float* Wo   = (const float*)d_in[6];
    const float* qnw  = (const float*)d_in[7];
    const float* knw  = (const float*)d_in[8];

    char* ws = (char*)d_ws;
    bf16* xb    = (bf16*)(ws);                 // 33,554,432 B  [8192][2048]
    bf16* wqkvT = (bf16*)(ws + 33554432);      // 12,582,912 B  [3072][2048]
    bf16* woT   = (bf16*)(ws + 46137344);      //  8,388,608 B  [2048][2048]
    bf16* qh    = (bf16*)(ws + 54525952);      // 33,554,432 B  [2][16][4096][128]
    bf16* kh    = (bf16*)(ws + 88080384);      //  8,388,608 B  [2][4][4096][128]
    bf16* vt    = (bf16*)(ws + 96468992);      //  8,388,608 B  [2][4][128][4096] -> total 100 MiB
    bf16* ao    = xb;                          // alias: xb dead after GEMM1
    bf16* qkv   = (bf16*)d_out;                // d_out as scratch: overwritten by GEMM2

    cvt_bf16_kernel<<<8192, 256, 0, stream>>>(x, xb, 16777216);
    transpose_wqkv_kernel<<<dim3(64, 96), 256, 0, stream>>>(Wq, Wk, Wv, wqkvT);
    transpose_w_kernel<<<dim3(64, 64), 256, 0, stream>>>(Wo, woT);
    // GEMM1: 128x192 tiles -> 1024 blocks = 2 exact rounds at 2 blocks/CU (R14 best)
    gemmocc_kernel<3, false><<<1024, 512, 0, stream>>>(xb, wqkvT, (void*)qkv, 8192, 3072, 2048, 16);
    normrope_vtrans_kernel<<<41472, 256, 0, stream>>>(qkv, cosT, sinT, qnw, knw, qh, kh, vt);
    attn_kernel<<<512, 512, 0, stream>>>(qh, kh, vt, ao);
    // GEMM2: 128x128 tiles -> 1024 blocks = 2 exact rounds at 2 blocks/CU (R14 best)
    gemmocc_kernel<2, true><<<1024, 512, 0, stream>>>(ao, woT, d_out, 8192, 2048, 2048, 16);
}

// Round 17
// 331.777 us; speedup vs baseline: 1.4305x; 1.0183x over previous
//
#include <hip/hip_runtime.h>
#include <hip/hip_bf16.h>

typedef __hip_bfloat16 bf16;
typedef __attribute__((ext_vector_type(8))) __bf16 bf16x8;
typedef __attribute__((ext_vector_type(4))) float f32x4;

#define MFMA16(a, b, c) __builtin_amdgcn_mfma_f32_16x16x32_bf16((a), (b), (c), 0, 0, 0)

static __device__ __forceinline__ void gload_lds16(const void* g, void* l) {
    typedef const __attribute__((address_space(1))) unsigned gq_t;
    typedef __attribute__((address_space(3))) unsigned ls_t;
    __builtin_amdgcn_global_load_lds((gq_t*)g, (ls_t*)l, 16, 0, 0);
}

static __device__ __forceinline__ unsigned short f2bfbits(float f) {
    bf16 h = __float2bfloat16(f);
    return *reinterpret_cast<unsigned short*>(&h);
}

// ---------------- prepass: f32 -> bf16 cast of x ----------------
__global__ __launch_bounds__(256) void cvt_bf16_kernel(const float* __restrict__ in,
                                                       bf16* __restrict__ out, int n) {
    int i = (blockIdx.x * 256 + threadIdx.x) * 8;
    if (i < n) {
        float4 a = *reinterpret_cast<const float4*>(in + i);
        float4 b = *reinterpret_cast<const float4*>(in + i + 4);
        bf16 tmp[8];
        tmp[0] = __float2bfloat16(a.x); tmp[1] = __float2bfloat16(a.y);
        tmp[2] = __float2bfloat16(a.z); tmp[3] = __float2bfloat16(a.w);
        tmp[4] = __float2bfloat16(b.x); tmp[5] = __float2bfloat16(b.y);
        tmp[6] = __float2bfloat16(b.z); tmp[7] = __float2bfloat16(b.w);
        *reinterpret_cast<uint4*>(out + i) = *reinterpret_cast<const uint4*>(tmp);
    }
}

// ---------------- prepass: transpose Wq|Wk|Wv -> [3072][2048] bf16 ----------------
__global__ __launch_bounds__(256) void transpose_wqkv_kernel(const float* __restrict__ Wq,
                                                             const float* __restrict__ Wk,
                                                             const float* __restrict__ Wv,
                                                             bf16* __restrict__ out) {
    __shared__ float tile[32][33];
    int k0 = blockIdx.x * 32;   // along K (2048)
    int n0 = blockIdx.y * 32;   // along N (3072)
    int tx = threadIdx.x & 31, ty = threadIdx.x >> 5;  // 32 x 8
#pragma unroll
    for (int i = 0; i < 4; ++i) {
        int k = k0 + ty + i * 8, n = n0 + tx;
        float v;
        if (n < 2048)      v = Wq[(size_t)k * 2048 + n];
        else if (n < 2560) v = Wk[(size_t)k * 512 + (n - 2048)];
        else               v = Wv[(size_t)k * 512 + (n - 2560)];
        tile[ty + i * 8][tx] = v;
    }
    __syncthreads();
#pragma unroll
    for (int i = 0; i < 4; ++i)
        out[(size_t)(n0 + ty + i * 8) * 2048 + k0 + tx] = __float2bfloat16(tile[tx][ty + i * 8]);
}

// ---------------- prepass: transpose square W (2048x2048) -> bf16 ----------------
__global__ __launch_bounds__(256) void transpose_w_kernel(const float* __restrict__ in,
                                                          bf16* __restrict__ out) {
    __shared__ float tile[32][33];
    int k0 = blockIdx.x * 32, n0 = blockIdx.y * 32;
    int tx = threadIdx.x & 31, ty = threadIdx.x >> 5;
#pragma unroll
    for (int i = 0; i < 4; ++i)
        tile[ty + i * 8][tx] = in[(size_t)(k0 + ty + i * 8) * 2048 + n0 + tx];
    __syncthreads();
#pragma unroll
    for (int i = 0; i < 4; ++i)
        out[(size_t)(n0 + ty + i * 8) * 2048 + k0 + tx] = __float2bfloat16(tile[tx][ty + i * 8]);
}

// ---------------- occupancy-GEMM (R14-verified): 128 x (NFRAG*64) tile, 2 blocks/CU ----
template <int NFRAG, bool OUT_F32>
__global__ __launch_bounds__(512, 4) void gemmocc_kernel(const bf16* __restrict__ A,
                                                         const bf16* __restrict__ BT,
                                                         void* __restrict__ Cv,
                                                         int M, int N, int K, int nbn) {
    constexpr int BN = NFRAG * 64;
    constexpr int PB = NFRAG;          // B pieces per K-tile (1 gload/thread each)
    __shared__ bf16 As[2][128 * 64];   // 16 KiB per slot
    __shared__ bf16 Bs[2][BN * 64];
    int t = threadIdx.x;
    int lane = t & 63, w = t >> 6;
    int wm = w >> 2, wn = w & 3;       // 2 x 4 wave grid; per-wave C = 64 x NFRAG*16
    int lr = lane & 15, lq = lane >> 4;
    int lin = blockIdx.x;
    int cpx = gridDim.x >> 3;          // bijective XCD-chunked swizzle (grid % 8 == 0)
    int wg = (lin & 7) * cpx + (lin >> 3);
    int bm = wg / nbn, bn = wg % nbn;
    const bf16* Ab = A + (size_t)bm * 128 * K;
    const bf16* Bb = BT + (size_t)bn * BN * K;

    auto stA = [&](int slot, int kt, int piece) {
        int idx = piece * 512 + t;
        int r = idx >> 3, c8 = idx & 7;
        gload_lds16(Ab + (size_t)r * K + kt * 64 + ((c8 ^ (r & 7)) * 8), &As[slot][idx * 8]);
    };
    auto stB = [&](int slot, int kt, int piece) {
        int idx = piece * 512 + t;
        int r = idx >> 3, c8 = idx & 7;
        gload_lds16(Bb + (size_t)r * K + kt * 64 + ((c8 ^ (r & 7)) * 8), &Bs[slot][idx * 8]);
    };

    f32x4 acc[4][NFRAG] = {};
    bf16x8 bq[NFRAG][2], af[2][2];

    auto readB = [&](int slot) {
#pragma unroll
        for (int n = 0; n < NFRAG; ++n)
#pragma unroll
            for (int ks = 0; ks < 2; ++ks) {
                int ro = wn * (NFRAG * 16) + n * 16 + lr;
                int ch = (ks * 4 + lq) ^ (ro & 7);
                bq[n][ks] = *reinterpret_cast<const bf16x8*>(&Bs[slot][ro * 64 + ch * 8]);
            }
    };
    auto readA = [&](int mbase, int slot) {
#pragma unroll
        for (int mi = 0; mi < 2; ++mi)
#pragma unroll
            for (int ks = 0; ks < 2; ++ks) {
                int ro = wm * 64 + (mbase + mi) * 16 + lr;
                int ch = (ks * 4 + lq) ^ (ro & 7);
                af[mi][ks] = *reinterpret_cast<const bf16x8*>(&As[slot][ro * 64 + ch * 8]);
            }
    };
    auto mf = [&](int mbase) {
#pragma unroll
        for (int mi = 0; mi < 2; ++mi)
#pragma unroll
            for (int n = 0; n < NFRAG; ++n)
#pragma unroll
                for (int ks = 0; ks < 2; ++ks)
                    acc[mbase + mi][n] = MFMA16(af[mi][ks], bq[n][ks], acc[mbase + mi][n]);
    };

#define GATE_PB() asm volatile("s_waitcnt vmcnt(%0)" :: "i"(PB) : "memory")
#define PHASE_TAIL()                                                       \
    do {                                                                   \
        __builtin_amdgcn_s_barrier();                                      \
        asm volatile("s_waitcnt lgkmcnt(0)" ::: "memory");                 \
    } while (0)
#define MFMA_CLUSTER(mb)                                                   \
    do {                                                                   \
        __builtin_amdgcn_s_setprio(1);                                     \
        mf(mb);                                                            \
        __builtin_amdgcn_s_setprio(0);                                     \
        __builtin_amdgcn_s_barrier();                                      \
    } while (0)

    int nkt = K >> 6;   // even (K=2048 -> 32)
    stA(0, 0, 0); stA(0, 0, 1);
#pragma unroll
    for (int p = 0; p < PB; ++p) stB(0, 0, p);
#pragma unroll
    for (int p = 0; p < PB; ++p) stB(1, 1, p);
    GATE_PB();
    __builtin_amdgcn_s_barrier();

    int nI = nkt >> 1;
    for (int I = 0; I < nI; ++I) {
        int T = I << 1;
        bool s2 = (T + 2) < nkt;
        // ---- ph1: tile T (s0), m0-1; stage A(T+1) -> s1 ----
        readB(0); readA(0, 0);
        stA(1, T + 1, 0); stA(1, T + 1, 1);
        PHASE_TAIL();
        MFMA_CLUSTER(0);
        // ---- ph2: m2-3; stage B(T+2) -> s0; GATE certifies T+1 ----
        readA(2, 0);
        if (s2) {
#pragma unroll
            for (int p = 0; p < PB; ++p) stB(0, T + 2, p);
            GATE_PB();
        } else {
            asm volatile("s_waitcnt vmcnt(0)" ::: "memory");
        }
        PHASE_TAIL();
        MFMA_CLUSTER(2);
        // ---- ph3: tile T+1 (s1), m0-1; stage A(T+2) -> s0 ----
        readB(1); readA(0, 1);
        if (s2) { stA(0, T + 2, 0); stA(0, T + 2, 1); }
        PHASE_TAIL();
        MFMA_CLUSTER(0);
        // ---- ph4: m2-3; stage B(T+3) -> s1; GATE certifies T+2 ----
        readA(2, 1);
        if (s2) {
#pragma unroll
            for (int p = 0; p < PB; ++p) stB(1, T + 3, p);
            GATE_PB();
        } else {
            asm volatile("s_waitcnt vmcnt(0)" ::: "memory");
        }
        PHASE_TAIL();
        MFMA_CLUSTER(2);
    }
#undef GATE_PB
#undef PHASE_TAIL
#undef MFMA_CLUSTER

#pragma unroll
    for (int m = 0; m < 4; ++m)
#pragma unroll
        for (int n = 0; n < NFRAG; ++n) {
            int row = bm * 128 + wm * 64 + m * 16 + lq * 4;
            int col = bn * BN + wn * (NFRAG * 16) + n * 16 + lr;
#pragma unroll
            for (int j = 0; j < 4; ++j) {
                if (OUT_F32)
                    ((float*)Cv)[(size_t)(row + j) * N + col] = acc[m][n][j];
                else
                    ((bf16*)Cv)[(size_t)(row + j) * N + col] = __float2bfloat16(acc[m][n][j]);
            }
        }
}

// ---------------- fused RMSNorm+RoPE (Q,K) and V-transpose ----------------
__global__ __launch_bounds__(256) void normrope_vtrans_kernel(const bf16* __restrict__ qkv,
                                                              const float* __restrict__ cosT,
                                                              const float* __restrict__ sinT,
                                                              const float* __restrict__ qnw,
                                                              const float* __restrict__ knw,
                                                              bf16* __restrict__ qh,
                                                              bf16* __restrict__ kh,
                                                              bf16* __restrict__ vt) {
    __shared__ bf16 tile[64][132];   // used by vtrans blocks only
    int t = threadIdx.x;
    int blk = blockIdx.x;
    if (blk < 40960) {
        int lane = t & 63, wv = t >> 6;
        int r = blk / 5;
        int s = (blk % 5) * 4 + wv;     // slot 0..19: 0-15 Q heads, 16-19 K groups
        int b = r >> 12, l = r & 4095;
        int e0 = lane * 2;
        const bf16* src = qkv + (size_t)r * 3072 + s * 128;
        ushort2 xu = *reinterpret_cast<const ushort2*>(src + e0);
        float v0 = __uint_as_float((unsigned)xu.x << 16);
        float v1 = __uint_as_float((unsigned)xu.y << 16);
        float ss = v0 * v0 + v1 * v1;
#pragma unroll
        for (int d = 1; d < 64; d <<= 1) ss += __shfl_xor(ss, d, 64);
        float rn = rsqrtf(ss * (1.0f / 128.0f) + 1e-6f);
        const float* wn = (s < 16) ? qnw : knw;
        float2 wv2 = *reinterpret_cast<const float2*>(wn + e0);
        float xn0 = v0 * rn * wv2.x;
        float xn1 = v1 * rn * wv2.y;
        float xp0 = __shfl_xor(xn0, 32, 64);
        float xp1 = __shfl_xor(xn1, 32, 64);
        float r0 = (lane < 32) ? -xp0 : xp0;
        float r1 = (lane < 32) ? -xp1 : xp1;
        float2 c2 = *reinterpret_cast<const float2*>(cosT + (size_t)l * 128 + e0);
        float2 s2 = *reinterpret_cast<const float2*>(sinT + (size_t)l * 128 + e0);
        float o0 = xn0 * c2.x + r0 * s2.x;
        float o1 = xn1 * c2.y + r1 * s2.y;
        ushort2 ou;
        if (s < 16) {
            const float scl = 0.0625f * 1.44269504088896f;  // SCALE * log2(e) folded into q
            ou.x = f2bfbits(o0 * scl);
            ou.y = f2bfbits(o1 * scl);
            bf16* dst = qh + ((size_t)(b * 16 + s) * 4096 + l) * 128;
            *reinterpret_cast<ushort2*>(dst + e0) = ou;
        } else {
            int g = s - 16;
            ou.x = f2bfbits(o0);
            ou.y = f2bfbits(o1);
            int sw = (l & 7) << 3;   // bits >=3: pair adjacency + 4B alignment preserved
            bf16* dst = kh + ((size_t)(b * 4 + g) * 4096 + l) * 128;
            *reinterpret_cast<ushort2*>(dst + (e0 ^ sw)) = ou;
        }
    } else {
        int bid2 = blk - 40960;          // 0..511
        int l0 = (bid2 & 63) * 64;
        int bg = bid2 >> 6;              // b*4+g
        int b = bg >> 2, g = bg & 3;
        const bf16* src = qkv + ((size_t)(b * 4096 + l0)) * 3072 + 2560 + g * 128;
#pragma unroll
        for (int i = 0; i < 4; ++i) {
            int c = i * 256 + t;
            int r = c >> 4, c16 = c & 15;
            uint4 v = *reinterpret_cast<const uint4*>(src + (size_t)r * 3072 + c16 * 8);
            *reinterpret_cast<uint2*>(&tile[r][c16 * 8]) = make_uint2(v.x, v.y);
            *reinterpret_cast<uint2*>(&tile[r][c16 * 8 + 4]) = make_uint2(v.z, v.w);
        }
        __syncthreads();
        bf16* dst = vt + (size_t)bg * 128 * 4096 + l0;
        int cj = t & 63;
        int pos = (cj & 0x23) | ((cj & 16) >> 2) | ((cj & 12) << 1);  // sigma(cj)
#pragma unroll
        for (int dd = 0; dd < 32; ++dd) {
            int d = (t >> 6) * 32 + dd;
            dst[(size_t)d * 4096 + (pos ^ ((d & 7) << 3))] = tile[cj][d];
        }
    }
}

// ---------------- sliding-window flash attention: QBLK=128, 4 waves, LPT order ----------------
// 1024 blocks (2 resident + 2 queued per CU -> dynamic balancing). Per-wave inner loop
// identical to R16 (32 q-rows, 2 groups). LPT: qi = 31 - ((bid>>3)&31) puts longest
// windows first in each XCD queue; shorts fill the tail. bh = (bid&7)*4 + (bid>>8)
// keeps each XCD's K/V set at 2 MB (L2-resident). Single barrier per KV-tile.
__global__ __launch_bounds__(256, 2) void attn_kernel(const bf16* __restrict__ qh,
                                                      const bf16* __restrict__ kh,
                                                      const bf16* __restrict__ vt,
                                                      bf16* __restrict__ ao) {
    __shared__ bf16 Ks[2][64 * 128];    // 32 KiB
    __shared__ bf16 Vs[2][128 * 64];    // 32 KiB -> 64 KiB total
    int t = threadIdx.x;
    int lane = t & 63, w = t >> 6;      // 4 waves
    int lr = lane & 15, lq = lane >> 4;
    int bid = blockIdx.x;
    int bh = (bid & 7) * 4 + (bid >> 8);       // XCD-resident K/V mapping (bijective, 1024 blocks)
    int qi_chunk = 31 - ((bid >> 3) & 31);     // LPT: longest windows first in queue order
    int qs = qi_chunk * 128;
    int b = bh >> 4, h = bh & 15, g = (h >> 2) & 3;
    int row0 = qs + w * 32;
    const bf16* qp = qh + ((size_t)(b * 16 + h) * 4096 + row0) * 128;
    const bf16* kp = kh + (size_t)(b * 4 + g) * 4096 * 128;
    const bf16* vp = vt + (size_t)(b * 4 + g) * 128 * 4096;

    bf16x8 aq[2][4];
#pragma unroll
    for (int g2 = 0; g2 < 2; ++g2)
#pragma unroll
        for (int kk = 0; kk < 4; ++kk)
            aq[g2][kk] = *reinterpret_cast<const bf16x8*>(qp + (size_t)(g2 * 16 + lr) * 128 + kk * 32 + lq * 8);

    // all-ones bf16 fragment: row-sum collector B-operand (k-order invariant)
    union { unsigned short u[8]; bf16x8 v; } onesu;
#pragma unroll
    for (int k = 0; k < 8; ++k) onesu.u[k] = 0x3F80;
    bf16x8 ones = onesu.v;

    f32x4 o0[8] = {}, o1[8] = {};
    f32x4 osum0 = {}, osum1 = {};            // D-row = q (lq*4+j), replicated over lr
    int qi0 = row0 + lr, qi1 = row0 + 16 + lr;
    int sA = max(0, row0 - 1023) >> 6;
    int sB = max(0, row0 + 16 - 1023) >> 6;
    int t1w = row0 >> 6;                     // diagonal tile (row0 % 32 == 0: both groups)
    int t0w = sA;
    int t0 = max(0, qs - 1023) >> 6;         // block-level range
    int t1 = (qs + 127) >> 6;

    auto stage = [&](int buf, int kt) {
        int j0 = kt * 64;
        const bf16* kg = kp + (size_t)j0 * 128;  // contiguous 16 KB (pre-swizzled)
#pragma unroll
        for (int i = 0; i < 4; ++i) {
            int c = i * 256 + t;                 // 0..1023 chunks of 16B
            gload_lds16(kg + c * 8, &Ks[buf][c * 8]);
        }
#pragma unroll
        for (int i = 0; i < 4; ++i) {
            int c = i * 256 + t;
            int d = c >> 3, co = (c & 7) * 8;
            gload_lds16(vp + (size_t)d * 4096 + j0 + co, &Vs[buf][c * 8]);
        }
    };

    stage(0, t0);                            // prologue stage of tile t0
    int cur = 0;

    for (int kt = t0; kt <= t1; ++kt) {
        asm volatile("s_waitcnt vmcnt(0)" ::: "memory");   // drain own stage loads
        __builtin_amdgcn_s_barrier();        // tile kt resident; compute(kt-1) done everywhere
        if (kt < t1) stage(cur ^ 1, kt + 1); // WAR safe: slot^1's readers finished pre-barrier
        if (kt >= t0w && kt <= t1w) {        // wave-uniform activity window
            int j0 = kt * 64;
            f32x4 s0[4] = {}, s1[4] = {};
            __builtin_amdgcn_s_setprio(1);
#pragma unroll
            for (int jt = 0; jt < 4; ++jt) {
                int r = jt * 16 + lr;
                int rs = (r & 7) << 3;
#pragma unroll
                for (int kk = 0; kk < 4; ++kk) {
                    int c = kk * 32 + lq * 8;
                    bf16x8 bk = *reinterpret_cast<const bf16x8*>(&Ks[cur][r * 128 + (c ^ rs)]);
                    s0[jt] = MFMA16(bk, aq[0][kk], s0[jt]);
                    s1[jt] = MFMA16(bk, aq[1][kk], s1[jt]);
                }
            }
            __builtin_amdgcn_s_setprio(0);
            if (kt <= sA + 1 || kt == t1w) {
#pragma unroll
                for (int jt = 0; jt < 4; ++jt)
#pragma unroll
                    for (int j = 0; j < 4; ++j) {
                        int kj = j0 + jt * 16 + lq * 4 + j;
                        if (!(kj <= qi0 && kj > qi0 - 1024)) s0[jt][j] = -1e30f;
                    }
            }
            if (kt <= sB + 1 || kt == t1w) {
#pragma unroll
                for (int jt = 0; jt < 4; ++jt)
#pragma unroll
                    for (int j = 0; j < 4; ++j) {
                        int kj = j0 + jt * 16 + lq * 4 + j;
                        if (!(kj <= qi1 && kj > qi1 - 1024)) s1[jt][j] = -1e30f;
                    }
            }
            unsigned pk0[4][2], pk1[4][2];
#pragma unroll
            for (int jt = 0; jt < 4; ++jt)
#pragma unroll
                for (int hh = 0; hh < 2; ++hh) {
                    float p0 = exp2f(s0[jt][2 * hh] - 11.5415603f);
                    float p1 = exp2f(s0[jt][2 * hh + 1] - 11.5415603f);
                    asm("v_cvt_pk_bf16_f32 %0, %1, %2" : "=v"(pk0[jt][hh]) : "v"(p0), "v"(p1));
                }
#pragma unroll
            for (int jt = 0; jt < 4; ++jt)
#pragma unroll
                for (int hh = 0; hh < 2; ++hh) {
                    float p0 = exp2f(s1[jt][2 * hh] - 11.5415603f);
                    float p1 = exp2f(s1[jt][2 * hh + 1] - 11.5415603f);
                    asm("v_cvt_pk_bf16_f32 %0, %1, %2" : "=v"(pk1[jt][hh]) : "v"(p0), "v"(p1));
                }
            __builtin_amdgcn_s_setprio(1);
#pragma unroll
            for (int kk2 = 0; kk2 < 2; ++kk2) {
                union { unsigned u[4]; bf16x8 v; } pu0, pu1;
                pu0.u[0] = pk0[2 * kk2][0]; pu0.u[1] = pk0[2 * kk2][1];
                pu0.u[2] = pk0[2 * kk2 + 1][0]; pu0.u[3] = pk0[2 * kk2 + 1][1];
                pu1.u[0] = pk1[2 * kk2][0]; pu1.u[1] = pk1[2 * kk2][1];
                pu1.u[2] = pk1[2 * kk2 + 1][0]; pu1.u[3] = pk1[2 * kk2 + 1][1];
                osum0 = MFMA16(pu0.v, ones, osum0);
                osum1 = MFMA16(pu1.v, ones, osum1);
#pragma unroll
                for (int dt = 0; dt < 8; ++dt) {
                    int r = dt * 16 + lr;
                    int c = kk2 * 32 + lq * 8;
                    bf16x8 bv = *reinterpret_cast<const bf16x8*>(&Vs[cur][r * 64 + (c ^ ((r & 7) << 3))]);
                    o0[dt] = MFMA16(pu0.v, bv, o0[dt]);
                    o1[dt] = MFMA16(pu1.v, bv, o1[dt]);
                }
            }
            __builtin_amdgcn_s_setprio(0);
        }
        cur ^= 1;
    }
    // ---- epilogue: linv already on the right lanes (D-row = q), no shuffles ----
    float lv0[4], lv1[4];
#pragma unroll
    for (int j = 0; j < 4; ++j) {
        lv0[j] = 1.0f / osum0[j];
        lv1[j] = 1.0f / osum1[j];
    }
#pragma unroll
    for (int dt = 0; dt < 8; ++dt)
#pragma unroll
        for (int j = 0; j < 4; ++j) {
            size_t base = (size_t)(b * 4096 + row0 + lq * 4 + j) * 2048 + h * 128 + dt * 16 + lr;
            ao[base] = __float2bfloat16(o0[dt][j] * lv0[j]);
            ao[base + (size_t)16 * 2048] = __float2bfloat16(o1[dt][j] * lv1[j]);
        }
}

extern "C" void kernel_launch(void* const* d_in, const int* in_sizes, int n_in,
                              void* d_out, int out_size, void* d_ws, size_t ws_size,
                              hipStream_t stream) {
    const float* x    = (const float*)d_in[0];
    const float* cosT = (const float*)d_in[1];
    const float* sinT = (const float*)d_in[2];
    const float* Wq   = (const float*)d_in[3];
    const float* Wk   = (const float*)d_in[4];
    const float* Wv   = (const float*)d_in[5];
    const float* Wo   = (const float*)d_in[6];
    const float* qnw  = (const float*)d_in[7];
    const float* knw  = (const float*)d_in[8];

    char* ws = (char*)d_ws;
    bf16* xb    = (bf16*)(ws);                 // 33,554,432 B  [8192][2048]
    bf16* wqkvT = (bf16*)(ws + 33554432);      // 12,582,912 B  [3072][2048]
    bf16* woT   = (bf16*)(ws + 46137344);      //  8,388,608 B  [2048][2048]
    bf16* qh    = (bf16*)(ws + 54525952);      // 33,554,432 B  [2][16][4096][128]
    bf16* kh    = (bf16*)(ws + 88080384);      //  8,388,608 B  [2][4][4096][128]
    bf16* vt    = (bf16*)(ws + 96468992);      //  8,388,608 B  [2][4][128][4096] -> total 100 MiB
    bf16* ao    = xb;                          // alias: xb dead after GEMM1
    bf16* qkv   = (bf16*)d_out;                // d_out as scratch: overwritten by GEMM2

    cvt_bf16_kernel<<<8192, 256, 0, stream>>>(x, xb, 16777216);
    transpose_wqkv_kernel<<<dim3(64, 96), 256, 0, stream>>>(Wq, Wk, Wv, wqkvT);
    transpose_w_kernel<<<dim3(64, 64), 256, 0, stream>>>(Wo, woT);
    // GEMM1: 128x192 tiles -> 1024 blocks = 2 exact rounds at 2 blocks/CU (R14 best)
    gemmocc_kernel<3, false><<<1024, 512, 0, stream>>>(xb, wqkvT, (void*)qkv, 8192, 3072, 2048, 16);
    normrope_vtrans_kernel<<<41472, 256, 0, stream>>>(qkv, cosT, sinT, qnw, knw, qh, kh, vt);
    attn_kernel<<<1024, 256, 0, stream>>>(qh, kh, vt, ao);
    // GEMM2: 128x128 tiles -> 1024 blocks = 2 exact rounds at 2 blocks/CU (R14 best)
    gemmocc_kernel<2, true><<<1024, 512, 0, stream>>>(ao, woT, d_out, 8192, 2048, 2048, 16);
}

// Round 18
// 300.679 us; speedup vs baseline: 1.5784x; 1.1034x over previous
//
#include <hip/hip_runtime.h>
#include <hip/hip_bf16.h>

typedef __hip_bfloat16 bf16;
typedef __attribute__((ext_vector_type(8))) __bf16 bf16x8;
typedef __attribute__((ext_vector_type(4))) float f32x4;

#define MFMA16(a, b, c) __builtin_amdgcn_mfma_f32_16x16x32_bf16((a), (b), (c), 0, 0, 0)

static __device__ __forceinline__ void gload_lds16(const void* g, void* l) {
    typedef const __attribute__((address_space(1))) unsigned gq_t;
    typedef __attribute__((address_space(3))) unsigned ls_t;
    __builtin_amdgcn_global_load_lds((gq_t*)g, (ls_t*)l, 16, 0, 0);
}

static __device__ __forceinline__ unsigned short f2bfbits(float f) {
    bf16 h = __float2bfloat16(f);
    return *reinterpret_cast<unsigned short*>(&h);
}

// ---------------- fused prepass: cvt x -> bf16 | transpose Wqkv | transpose Wo ----------------
// blocks [0,8192): cvt; [8192,14336): Wq|Wk|Wv transpose; [14336,18432): Wo transpose.
__global__ __launch_bounds__(256) void prep_kernel(const float* __restrict__ x,
                                                   const float* __restrict__ Wq,
                                                   const float* __restrict__ Wk,
                                                   const float* __restrict__ Wv,
                                                   const float* __restrict__ Wo,
                                                   bf16* __restrict__ xb,
                                                   bf16* __restrict__ wqkvT,
                                                   bf16* __restrict__ woT) {
    __shared__ float tile[32][33];
    int t = threadIdx.x;
    int blk = blockIdx.x;
    if (blk < 8192) {
        int i = (blk * 256 + t) * 8;
        float4 a = *reinterpret_cast<const float4*>(x + i);
        float4 b = *reinterpret_cast<const float4*>(x + i + 4);
        bf16 tmp[8];
        tmp[0] = __float2bfloat16(a.x); tmp[1] = __float2bfloat16(a.y);
        tmp[2] = __float2bfloat16(a.z); tmp[3] = __float2bfloat16(a.w);
        tmp[4] = __float2bfloat16(b.x); tmp[5] = __float2bfloat16(b.y);
        tmp[6] = __float2bfloat16(b.z); tmp[7] = __float2bfloat16(b.w);
        *reinterpret_cast<uint4*>(xb + i) = *reinterpret_cast<const uint4*>(tmp);
    } else if (blk < 14336) {
        int bid = blk - 8192;
        int k0 = (bid & 63) * 32;        // along K (2048)
        int n0 = (bid >> 6) * 32;        // along N (3072)
        int tx = t & 31, ty = t >> 5;    // 32 x 8
#pragma unroll
        for (int i = 0; i < 4; ++i) {
            int k = k0 + ty + i * 8, n = n0 + tx;
            float v;
            if (n < 2048)      v = Wq[(size_t)k * 2048 + n];
            else if (n < 2560) v = Wk[(size_t)k * 512 + (n - 2048)];
            else               v = Wv[(size_t)k * 512 + (n - 2560)];
            tile[ty + i * 8][tx] = v;
        }
        __syncthreads();
#pragma unroll
        for (int i = 0; i < 4; ++i)
            wqkvT[(size_t)(n0 + ty + i * 8) * 2048 + k0 + tx] = __float2bfloat16(tile[tx][ty + i * 8]);
    } else {
        int bid = blk - 14336;
        int k0 = (bid & 63) * 32, n0 = (bid >> 6) * 32;
        int tx = t & 31, ty = t >> 5;
#pragma unroll
        for (int i = 0; i < 4; ++i)
            tile[ty + i * 8][tx] = Wo[(size_t)(k0 + ty + i * 8) * 2048 + n0 + tx];
        __syncthreads();
#pragma unroll
        for (int i = 0; i < 4; ++i)
            woT[(size_t)(n0 + ty + i * 8) * 2048 + k0 + tx] = __float2bfloat16(tile[tx][ty + i * 8]);
    }
}

// ---------------- occupancy-GEMM (R14-verified): 128 x (NFRAG*64) tile, 2 blocks/CU ----
template <int NFRAG, bool OUT_F32>
__global__ __launch_bounds__(512, 4) void gemmocc_kernel(const bf16* __restrict__ A,
                                                         const bf16* __restrict__ BT,
                                                         void* __restrict__ Cv,
                                                         int M, int N, int K, int nbn) {
    constexpr int BN = NFRAG * 64;
    constexpr int PB = NFRAG;          // B pieces per K-tile (1 gload/thread each)
    __shared__ bf16 As[2][128 * 64];   // 16 KiB per slot
    __shared__ bf16 Bs[2][BN * 64];
    int t = threadIdx.x;
    int lane = t & 63, w = t >> 6;
    int wm = w >> 2, wn = w & 3;       // 2 x 4 wave grid; per-wave C = 64 x NFRAG*16
    int lr = lane & 15, lq = lane >> 4;
    int lin = blockIdx.x;
    int cpx = gridDim.x >> 3;          // bijective XCD-chunked swizzle (grid % 8 == 0)
    int wg = (lin & 7) * cpx + (lin >> 3);
    int bm = wg / nbn, bn = wg % nbn;
    const bf16* Ab = A + (size_t)bm * 128 * K;
    const bf16* Bb = BT + (size_t)bn * BN * K;

    auto stA = [&](int slot, int kt, int piece) {
        int idx = piece * 512 + t;
        int r = idx >> 3, c8 = idx & 7;
        gload_lds16(Ab + (size_t)r * K + kt * 64 + ((c8 ^ (r & 7)) * 8), &As[slot][idx * 8]);
    };
    auto stB = [&](int slot, int kt, int piece) {
        int idx = piece * 512 + t;
        int r = idx >> 3, c8 = idx & 7;
        gload_lds16(Bb + (size_t)r * K + kt * 64 + ((c8 ^ (r & 7)) * 8), &Bs[slot][idx * 8]);
    };

    f32x4 acc[4][NFRAG] = {};
    bf16x8 bq[NFRAG][2], af[2][2];

    auto readB = [&](int slot) {
#pragma unroll
        for (int n = 0; n < NFRAG; ++n)
#pragma unroll
            for (int ks = 0; ks < 2; ++ks) {
                int ro = wn * (NFRAG * 16) + n * 16 + lr;
                int ch = (ks * 4 + lq) ^ (ro & 7);
                bq[n][ks] = *reinterpret_cast<const bf16x8*>(&Bs[slot][ro * 64 + ch * 8]);
            }
    };
    auto readA = [&](int mbase, int slot) {
#pragma unroll
        for (int mi = 0; mi < 2; ++mi)
#pragma unroll
            for (int ks = 0; ks < 2; ++ks) {
                int ro = wm * 64 + (mbase + mi) * 16 + lr;
                int ch = (ks * 4 + lq) ^ (ro & 7);
                af[mi][ks] = *reinterpret_cast<const bf16x8*>(&As[slot][ro * 64 + ch * 8]);
            }
    };
    auto mf = [&](int mbase) {
#pragma unroll
        for (int mi = 0; mi < 2; ++mi)
#pragma unroll
            for (int n = 0; n < NFRAG; ++n)
#pragma unroll
                for (int ks = 0; ks < 2; ++ks)
                    acc[mbase + mi][n] = MFMA16(af[mi][ks], bq[n][ks], acc[mbase + mi][n]);
    };

#define GATE_PB() asm volatile("s_waitcnt vmcnt(%0)" :: "i"(PB) : "memory")
#define PHASE_TAIL()                                                       \
    do {                                                                   \
        __builtin_amdgcn_s_barrier();                                      \
        asm volatile("s_waitcnt lgkmcnt(0)" ::: "memory");                 \
    } while (0)
#define MFMA_CLUSTER(mb)                                                   \
    do {                                                                   \
        __builtin_amdgcn_s_setprio(1);                                     \
        mf(mb);                                                            \
        __builtin_amdgcn_s_setprio(0);                                     \
        __builtin_amdgcn_s_barrier();                                      \
    } while (0)

    int nkt = K >> 6;   // even (K=2048 -> 32)
    stA(0, 0, 0); stA(0, 0, 1);
#pragma unroll
    for (int p = 0; p < PB; ++p) stB(0, 0, p);
#pragma unroll
    for (int p = 0; p < PB; ++p) stB(1, 1, p);
    GATE_PB();
    __builtin_amdgcn_s_barrier();

    int nI = nkt >> 1;
    for (int I = 0; I < nI; ++I) {
        int T = I << 1;
        bool s2 = (T + 2) < nkt;
        // ---- ph1: tile T (s0), m0-1; stage A(T+1) -> s1 ----
        readB(0); readA(0, 0);
        stA(1, T + 1, 0); stA(1, T + 1, 1);
        PHASE_TAIL();
        MFMA_CLUSTER(0);
        // ---- ph2: m2-3; stage B(T+2) -> s0; GATE certifies T+1 ----
        readA(2, 0);
        if (s2) {
#pragma unroll
            for (int p = 0; p < PB; ++p) stB(0, T + 2, p);
            GATE_PB();
        } else {
            asm volatile("s_waitcnt vmcnt(0)" ::: "memory");
        }
        PHASE_TAIL();
        MFMA_CLUSTER(2);
        // ---- ph3: tile T+1 (s1), m0-1; stage A(T+2) -> s0 ----
        readB(1); readA(0, 1);
        if (s2) { stA(0, T + 2, 0); stA(0, T + 2, 1); }
        PHASE_TAIL();
        MFMA_CLUSTER(0);
        // ---- ph4: m2-3; stage B(T+3) -> s1; GATE certifies T+2 ----
        readA(2, 1);
        if (s2) {
#pragma unroll
            for (int p = 0; p < PB; ++p) stB(1, T + 3, p);
            GATE_PB();
        } else {
            asm volatile("s_waitcnt vmcnt(0)" ::: "memory");
        }
        PHASE_TAIL();
        MFMA_CLUSTER(2);
    }
#undef GATE_PB
#undef PHASE_TAIL
#undef MFMA_CLUSTER

#pragma unroll
    for (int m = 0; m < 4; ++m)
#pragma unroll
        for (int n = 0; n < NFRAG; ++n) {
            int row = bm * 128 + wm * 64 + m * 16 + lq * 4;
            int col = bn * BN + wn * (NFRAG * 16) + n * 16 + lr;
#pragma unroll
            for (int j = 0; j < 4; ++j) {
                if (OUT_F32)
                    ((float*)Cv)[(size_t)(row + j) * N + col] = acc[m][n][j];
                else
                    ((bf16*)Cv)[(size_t)(row + j) * N + col] = __float2bfloat16(acc[m][n][j]);
            }
        }
}

// ---------------- fused RMSNorm+RoPE (Q,K) and V-transpose ----------------
__global__ __launch_bounds__(256) void normrope_vtrans_kernel(const bf16* __restrict__ qkv,
                                                              const float* __restrict__ cosT,
                                                              const float* __restrict__ sinT,
                                                              const float* __restrict__ qnw,
                                                              const float* __restrict__ knw,
                                                              bf16* __restrict__ qh,
                                                              bf16* __restrict__ kh,
                                                              bf16* __restrict__ vt) {
    __shared__ bf16 tile[64][132];   // used by vtrans blocks only
    int t = threadIdx.x;
    int blk = blockIdx.x;
    if (blk < 40960) {
        int lane = t & 63, wv = t >> 6;
        int r = blk / 5;
        int s = (blk % 5) * 4 + wv;     // slot 0..19: 0-15 Q heads, 16-19 K groups
        int b = r >> 12, l = r & 4095;
        int e0 = lane * 2;
        const bf16* src = qkv + (size_t)r * 3072 + s * 128;
        ushort2 xu = *reinterpret_cast<const ushort2*>(src + e0);
        float v0 = __uint_as_float((unsigned)xu.x << 16);
        float v1 = __uint_as_float((unsigned)xu.y << 16);
        float ss = v0 * v0 + v1 * v1;
#pragma unroll
        for (int d = 1; d < 64; d <<= 1) ss += __shfl_xor(ss, d, 64);
        float rn = rsqrtf(ss * (1.0f / 128.0f) + 1e-6f);
        const float* wn = (s < 16) ? qnw : knw;
        float2 wv2 = *reinterpret_cast<const float2*>(wn + e0);
        float xn0 = v0 * rn * wv2.x;
        float xn1 = v1 * rn * wv2.y;
        float xp0 = __shfl_xor(xn0, 32, 64);
        float xp1 = __shfl_xor(xn1, 32, 64);
        float r0 = (lane < 32) ? -xp0 : xp0;
        float r1 = (lane < 32) ? -xp1 : xp1;
        float2 c2 = *reinterpret_cast<const float2*>(cosT + (size_t)l * 128 + e0);
        float2 s2 = *reinterpret_cast<const float2*>(sinT + (size_t)l * 128 + e0);
        float o0 = xn0 * c2.x + r0 * s2.x;
        float o1 = xn1 * c2.y + r1 * s2.y;
        ushort2 ou;
        if (s < 16) {
            const float scl = 0.0625f * 1.44269504088896f;  // SCALE * log2(e) folded into q
            ou.x = f2bfbits(o0 * scl);
            ou.y = f2bfbits(o1 * scl);
            bf16* dst = qh + ((size_t)(b * 16 + s) * 4096 + l) * 128;
            *reinterpret_cast<ushort2*>(dst + e0) = ou;
        } else {
            int g = s - 16;
            ou.x = f2bfbits(o0);
            ou.y = f2bfbits(o1);
            int sw = (l & 7) << 3;   // bits >=3: pair adjacency + 4B alignment preserved
            bf16* dst = kh + ((size_t)(b * 4 + g) * 4096 + l) * 128;
            *reinterpret_cast<ushort2*>(dst + (e0 ^ sw)) = ou;
        }
    } else {
        int bid2 = blk - 40960;          // 0..511
        int l0 = (bid2 & 63) * 64;
        int bg = bid2 >> 6;              // b*4+g
        int b = bg >> 2, g = bg & 3;
        const bf16* src = qkv + ((size_t)(b * 4096 + l0)) * 3072 + 2560 + g * 128;
#pragma unroll
        for (int i = 0; i < 4; ++i) {
            int c = i * 256 + t;
            int r = c >> 4, c16 = c & 15;
            uint4 v = *reinterpret_cast<const uint4*>(src + (size_t)r * 3072 + c16 * 8);
            *reinterpret_cast<uint2*>(&tile[r][c16 * 8]) = make_uint2(v.x, v.y);
            *reinterpret_cast<uint2*>(&tile[r][c16 * 8 + 4]) = make_uint2(v.z, v.w);
        }
        __syncthreads();
        bf16* dst = vt + (size_t)bg * 128 * 4096 + l0;
        int cj = t & 63;
        int pos = (cj & 0x23) | ((cj & 16) >> 2) | ((cj & 12) << 1);  // sigma(cj)
#pragma unroll
        for (int dd = 0; dd < 32; ++dd) {
            int d = (t >> 6) * 32 + dd;
            dst[(size_t)d * 4096 + (pos ^ ((d & 7) << 3))] = tile[cj][d];
        }
    }
}

// ---------------- sliding-window flash attention: QBLK=128, LPT, VALU-trimmed ----------------
// R17 structure + (a) softmax shift folded into QK^T accumulator init (MFMA C-in does
// the subtraction; deletes 32 v_sub per wave-tile), (b) __builtin_amdgcn_exp2f for bare
// v_exp_f32 (domain: <= 8.1; masked -1e30 -> exp2 -> 0).
__global__ __launch_bounds__(256, 2) void attn_kernel(const bf16* __restrict__ qh,
                                                      const bf16* __restrict__ kh,
                                                      const bf16* __restrict__ vt,
                                                      bf16* __restrict__ ao) {
    __shared__ bf16 Ks[2][64 * 128];    // 32 KiB
    __shared__ bf16 Vs[2][128 * 64];    // 32 KiB -> 64 KiB total
    int t = threadIdx.x;
    int lane = t & 63, w = t >> 6;      // 4 waves
    int lr = lane & 15, lq = lane >> 4;
    int bid = blockIdx.x;
    int bh = (bid & 7) * 4 + (bid >> 8);       // XCD-resident K/V mapping (bijective, 1024 blocks)
    int qi_chunk = 31 - ((bid >> 3) & 31);     // LPT: longest windows first in queue order
    int qs = qi_chunk * 128;
    int b = bh >> 4, h = bh & 15, g = (h >> 2) & 3;
    int row0 = qs + w * 32;
    const bf16* qp = qh + ((size_t)(b * 16 + h) * 4096 + row0) * 128;
    const bf16* kp = kh + (size_t)(b * 4 + g) * 4096 * 128;
    const bf16* vp = vt + (size_t)(b * 4 + g) * 128 * 4096;

    bf16x8 aq[2][4];
#pragma unroll
    for (int g2 = 0; g2 < 2; ++g2)
#pragma unroll
        for (int kk = 0; kk < 4; ++kk)
            aq[g2][kk] = *reinterpret_cast<const bf16x8*>(qp + (size_t)(g2 * 16 + lr) * 128 + kk * 32 + lq * 8);

    // all-ones bf16 fragment: row-sum collector B-operand (k-order invariant)
    union { unsigned short u[8]; bf16x8 v; } onesu;
#pragma unroll
    for (int k = 0; k < 8; ++k) onesu.u[k] = 0x3F80;
    bf16x8 ones = onesu.v;

    const float SH = 11.5415603f;            // shift in log2 space (pre-subtracted via C-in)
    f32x4 o0[8] = {}, o1[8] = {};
    f32x4 osum0 = {}, osum1 = {};            // D-row = q (lq*4+j), replicated over lr
    int qi0 = row0 + lr, qi1 = row0 + 16 + lr;
    int sA = max(0, row0 - 1023) >> 6;
    int sB = max(0, row0 + 16 - 1023) >> 6;
    int t1w = row0 >> 6;                     // diagonal tile (row0 % 32 == 0: both groups)
    int t0w = sA;
    int t0 = max(0, qs - 1023) >> 6;         // block-level range
    int t1 = (qs + 127) >> 6;

    auto stage = [&](int buf, int kt) {
        int j0 = kt * 64;
        const bf16* kg = kp + (size_t)j0 * 128;  // contiguous 16 KB (pre-swizzled)
#pragma unroll
        for (int i = 0; i < 4; ++i) {
            int c = i * 256 + t;                 // 0..1023 chunks of 16B
            gload_lds16(kg + c * 8, &Ks[buf][c * 8]);
        }
#pragma unroll
        for (int i = 0; i < 4; ++i) {
            int c = i * 256 + t;
            int d = c >> 3, co = (c & 7) * 8;
            gload_lds16(vp + (size_t)d * 4096 + j0 + co, &Vs[buf][c * 8]);
        }
    };

    stage(0, t0);                            // prologue stage of tile t0
    int cur = 0;

    for (int kt = t0; kt <= t1; ++kt) {
        asm volatile("s_waitcnt vmcnt(0)" ::: "memory");   // drain own stage loads
        __builtin_amdgcn_s_barrier();        // tile kt resident; compute(kt-1) done everywhere
        if (kt < t1) stage(cur ^ 1, kt + 1); // WAR safe: slot^1's readers finished pre-barrier
        if (kt >= t0w && kt <= t1w) {        // wave-uniform activity window
            int j0 = kt * 64;
            f32x4 s0[4], s1[4];
#pragma unroll
            for (int jt = 0; jt < 4; ++jt) {
                s0[jt][0] = -SH; s0[jt][1] = -SH; s0[jt][2] = -SH; s0[jt][3] = -SH;
                s1[jt][0] = -SH; s1[jt][1] = -SH; s1[jt][2] = -SH; s1[jt][3] = -SH;
            }
            __builtin_amdgcn_s_setprio(1);
#pragma unroll
            for (int jt = 0; jt < 4; ++jt) {
                int r = jt * 16 + lr;
                int rs = (r & 7) << 3;
#pragma unroll
                for (int kk = 0; kk < 4; ++kk) {
                    int c = kk * 32 + lq * 8;
                    bf16x8 bk = *reinterpret_cast<const bf16x8*>(&Ks[cur][r * 128 + (c ^ rs)]);
                    s0[jt] = MFMA16(bk, aq[0][kk], s0[jt]);
                    s1[jt] = MFMA16(bk, aq[1][kk], s1[jt]);
                }
            }
            __builtin_amdgcn_s_setprio(0);
            if (kt <= sA + 1 || kt == t1w) {
#pragma unroll
                for (int jt = 0; jt < 4; ++jt)
#pragma unroll
                    for (int j = 0; j < 4; ++j) {
                        int kj = j0 + jt * 16 + lq * 4 + j;
                        if (!(kj <= qi0 && kj > qi0 - 1024)) s0[jt][j] = -1e30f;
                    }
            }
            if (kt <= sB + 1 || kt == t1w) {
#pragma unroll
                for (int jt = 0; jt < 4; ++jt)
#pragma unroll
                    for (int j = 0; j < 4; ++j) {
                        int kj = j0 + jt * 16 + lq * 4 + j;
                        if (!(kj <= qi1 && kj > qi1 - 1024)) s1[jt][j] = -1e30f;
                    }
            }
            unsigned pk0[4][2], pk1[4][2];
#pragma unroll
            for (int jt = 0; jt < 4; ++jt)
#pragma unroll
                for (int hh = 0; hh < 2; ++hh) {
                    float p0 = __builtin_amdgcn_exp2f(s0[jt][2 * hh]);
                    float p1 = __builtin_amdgcn_exp2f(s0[jt][2 * hh + 1]);
                    asm("v_cvt_pk_bf16_f32 %0, %1, %2" : "=v"(pk0[jt][hh]) : "v"(p0), "v"(p1));
                }
#pragma unroll
            for (int jt = 0; jt < 4; ++jt)
#pragma unroll
                for (int hh = 0; hh < 2; ++hh) {
                    float p0 = __builtin_amdgcn_exp2f(s1[jt][2 * hh]);
                    float p1 = __builtin_amdgcn_exp2f(s1[jt][2 * hh + 1]);
                    asm("v_cvt_pk_bf16_f32 %0, %1, %2" : "=v"(pk1[jt][hh]) : "v"(p0), "v"(p1));
                }
            __builtin_amdgcn_s_setprio(1);
#pragma unroll
            for (int kk2 = 0; kk2 < 2; ++kk2) {
                union { unsigned u[4]; bf16x8 v; } pu0, pu1;
                pu0.u[0] = pk0[2 * kk2][0]; pu0.u[1] = pk0[2 * kk2][1];
                pu0.u[2] = pk0[2 * kk2 + 1][0]; pu0.u[3] = pk0[2 * kk2 + 1][1];
                pu1.u[0] = pk1[2 * kk2][0]; pu1.u[1] = pk1[2 * kk2][1];
                pu1.u[2] = pk1[2 * kk2 + 1][0]; pu1.u[3] = pk1[2 * kk2 + 1][1];
                osum0 = MFMA16(pu0.v, ones, osum0);
                osum1 = MFMA16(pu1.v, ones, osum1);
#pragma unroll
                for (int dt = 0; dt < 8; ++dt) {
                    int r = dt * 16 + lr;
                    int c = kk2 * 32 + lq * 8;
                    bf16x8 bv = *reinterpret_cast<const bf16x8*>(&Vs[cur][r * 64 + (c ^ ((r & 7) << 3))]);
                    o0[dt] = MFMA16(pu0.v, bv, o0[dt]);
                    o1[dt] = MFMA16(pu1.v, bv, o1[dt]);
                }
            }
            __builtin_amdgcn_s_setprio(0);
        }
        cur ^= 1;
    }
    // ---- epilogue: linv already on the right lanes (D-row = q), no shuffles ----
    float lv0[4], lv1[4];
#pragma unroll
    for (int j = 0; j < 4; ++j) {
        lv0[j] = 1.0f / osum0[j];
        lv1[j] = 1.0f / osum1[j];
    }
#pragma unroll
    for (int dt = 0; dt < 8; ++dt)
#pragma unroll
        for (int j = 0; j < 4; ++j) {
            size_t base = (size_t)(b * 4096 + row0 + lq * 4 + j) * 2048 + h * 128 + dt * 16 + lr;
            ao[base] = __float2bfloat16(o0[dt][j] * lv0[j]);
            ao[base + (size_t)16 * 2048] = __float2bfloat16(o1[dt][j] * lv1[j]);
        }
}

extern "C" void kernel_launch(void* const* d_in, const int* in_sizes, int n_in,
                              void* d_out, int out_size, void* d_ws, size_t ws_size,
                              hipStream_t stream) {
    const float* x    = (const float*)d_in[0];
    const float* cosT = (const float*)d_in[1];
    const float* sinT = (const float*)d_in[2];
    const float* Wq   = (const float*)d_in[3];
    const float* Wk   = (const float*)d_in[4];
    const float* Wv   = (const float*)d_in[5];
    const float* Wo   = (const float*)d_in[6];
    const float* qnw  = (const float*)d_in[7];
    const float* knw  = (const float*)d_in[8];

    char* ws = (char*)d_ws;
    bf16* xb    = (bf16*)(ws);                 // 33,554,432 B  [8192][2048]
    bf16* wqkvT = (bf16*)(ws + 33554432);      // 12,582,912 B  [3072][2048]
    bf16* woT   = (bf16*)(ws + 46137344);      //  8,388,608 B  [2048][2048]
    bf16* qh    = (bf16*)(ws + 54525952);      // 33,554,432 B  [2][16][4096][128]
    bf16* kh    = (bf16*)(ws + 88080384);      //  8,388,608 B  [2][4][4096][128]
    bf16* vt    = (bf16*)(ws + 96468992);      //  8,388,608 B  [2][4][128][4096] -> total 100 MiB
    bf16* ao    = xb;                          // alias: xb dead after GEMM1
    bf16* qkv   = (bf16*)d_out;                // d_out as scratch: overwritten by GEMM2

    prep_kernel<<<18432, 256, 0, stream>>>(x, Wq, Wk, Wv, Wo, xb, wqkvT, woT);
    // GEMM1: 128x192 tiles -> 1024 blocks = 2 exact rounds at 2 blocks/CU (R14 best)
    gemmocc_kernel<3, false><<<1024, 512, 0, stream>>>(xb, wqkvT, (void*)qkv, 8192, 3072, 2048, 16);
    normrope_vtrans_kernel<<<41472, 256, 0, stream>>>(qkv, cosT, sinT, qnw, knw, qh, kh, vt);
    attn_kernel<<<1024, 256, 0, stream>>>(qh, kh, vt, ao);
    // GEMM2: 128x128 tiles -> 1024 blocks = 2 exact rounds at 2 blocks/CU (R14 best)
    gemmocc_kernel<2, true><<<1024, 512, 0, stream>>>(ao, woT, d_out, 8192, 2048, 2048, 16);
}